// Round 14
// baseline (109.544 us; speedup 1.0000x reference)
//
#include <hip/hip_runtime.h>
#include <hip/hip_bf16.h>
#include <string.h>
#include <stdint.h>

typedef __hip_bfloat16 bf16_t;
typedef float f32x4 __attribute__((ext_vector_type(4)));
typedef short bf16x8 __attribute__((ext_vector_type(8)));

static constexpr int Bn = 32, Ln = 4096, Cn = 64, Hn = 720, HPn = 768;
static constexpr float EPSf = 1e-5f;

static constexpr size_t OSR_SLICE = (size_t)Bn * Hn * Cn;   // f32 elements per K-slice per path

__device__ __forceinline__ short f2bf(float f) {
  bf16_t h = __float2bfloat16(f);
  unsigned short u; memcpy(&u, &h, 2);
  return (short)u;
}

__device__ __forceinline__ float sigm(float v) { return 1.f / (1.f + expf(-v)); }

// ================= kernel 1 (fused): wprep(1536, f32x4 reads) | scanA(512) =================
__global__ void __launch_bounds__(256) k_preA(
    const float* __restrict__ st_w, const float* __restrict__ tt_w,
    const float* __restrict__ x, const float* __restrict__ alpha,
    bf16_t* __restrict__ Wt, float* __restrict__ Spart,
    float* __restrict__ Psub, float* __restrict__ Pseg,
    float* __restrict__ Ssum, float* __restrict__ Ssq) {
  __shared__ __align__(16) char smem[20736];
  int bid = blockIdx.x, t = threadIdx.x;

  if (bid < 1536) {
    // -------- wprep: tw -> fragment-major AF (+Spart colsum partials), f32x4 global reads ------
    float (*tile)[65] = (float(*)[65])smem;             // 16640 B (pad 65: conflict-free emit)
    float (*cs16)[64] = (float(*)[64])(smem + 16640);   // 4096 B
    int p = bid / 768, rem = bid % 768;
    int lc = rem & 63, hc = rem >> 6;
    const float* W = p ? tt_w : st_w;                   // (4096, 720)
    int l0 = lc * 64, h0 = hc * 64;
    int g16 = t >> 4, c4l = (t & 15) * 4;
    int h = h0 + c4l;
    f32x4 ps = (f32x4){0.f, 0.f, 0.f, 0.f};
#pragma unroll
    for (int rr = 0; rr < 4; ++rr) {
      int r = rr * 16 + g16;
      const float* src = &W[(size_t)(l0 + r) * Hn + h];
      f32x4 v;
      if (h + 3 < Hn) {
        v = *reinterpret_cast<const f32x4*>(src);
      } else {
#pragma unroll
        for (int i = 0; i < 4; ++i) v[i] = (h + i < Hn) ? src[i] : 0.f;
      }
      tile[r][c4l + 0] = v[0]; tile[r][c4l + 1] = v[1];
      tile[r][c4l + 2] = v[2]; tile[r][c4l + 3] = v[3];
      ps += v;
    }
    *reinterpret_cast<f32x4*>(&cs16[g16][c4l]) = ps;
    __syncthreads();
    if (t < 64) {
      float s = 0.f;
#pragma unroll
      for (int g = 0; g < 16; ++g) s += cs16[g][t];
      Spart[((size_t)p * 64 + lc) * 768 + h0 + t] = s;
    }
    short* AF = (short*)Wt + (size_t)p * HPn * Ln;
#pragma unroll
    for (int u = 0; u < 2; ++u) {
      int uid = u * 256 + t;
      int ln = uid & 63, ktl = (uid >> 6) & 1, htl = uid >> 7;
      int fr = ln & 15, hi = ln >> 4;
      int ll = ktl * 32 + hi * 8;
      int hh = htl * 16 + fr;
      bf16x8 v;
#pragma unroll
      for (int e = 0; e < 8; ++e) v[e] = f2bf(tile[ll + e][hh]);
      size_t ht = (size_t)(h0 >> 4) + htl, ktg = (size_t)(l0 >> 5) + ktl;
      *reinterpret_cast<bf16x8*>(&AF[((ht * 128 + ktg) << 9) + ((size_t)ln << 3)]) = v;
    }
  } else {
    // ---------------- scanA: (c-quad x l-sub16) raw-x partials + seg reduce ----------------
    float (*lp)[64] = (float(*)[64])smem;
    float (*ls)[64] = (float(*)[64])(smem + 4096);
    float (*lq)[64] = (float(*)[64])(smem + 8192);
    int idx = bid - 1536;
    int b = idx >> 4, sg = idx & 15;
    int ty = t >> 6, tx = t & 63;
    int s = sg * 4 + ty;
    int c4 = (tx & 15) * 4, sub = tx >> 4;
    float a[4], k1[4];
#pragma unroll
    for (int i = 0; i < 4; ++i) { a[i] = sigm(alpha[c4 + i]); k1[i] = 1.f - a[i]; }
    const float* xb = x + ((size_t)b * Ln + s * 64 + sub * 16) * Cn + c4;
    float pr[4] = {0.f, 0.f, 0.f, 0.f}, sm[4] = {0.f, 0.f, 0.f, 0.f}, sq[4] = {0.f, 0.f, 0.f, 0.f};
#pragma unroll
    for (int j = 0; j < 16; ++j) {
      f32x4 v = *reinterpret_cast<const f32x4*>(xb + (size_t)j * Cn);
#pragma unroll
      for (int i = 0; i < 4; ++i) {
        sm[i] += v[i];
        sq[i] = fmaf(v[i], v[i], sq[i]);
        pr[i] = fmaf(a[i], pr[i], k1[i] * v[i]);
      }
    }
    *reinterpret_cast<f32x4*>(&Psub[(((size_t)b * 64 + s) * 4 + sub) * 64 + c4]) =
        (f32x4){pr[0], pr[1], pr[2], pr[3]};
#pragma unroll
    for (int i = 0; i < 4; ++i) {
      lp[ty * 4 + sub][c4 + i] = pr[i];
      ls[ty * 4 + sub][c4 + i] = sm[i];
      lq[ty * 4 + sub][c4 + i] = sq[i];
    }
    __syncthreads();
    int c = tx;
    float av = sigm(alpha[c]);
    float a16 = av * av; a16 *= a16; a16 *= a16; a16 *= a16;   // a^16
    float P = ((lp[ty * 4 + 0][c] * a16 + lp[ty * 4 + 1][c]) * a16 + lp[ty * 4 + 2][c]) * a16 + lp[ty * 4 + 3][c];
    int oidx = (b * 64 + s) * 64 + c;
    Pseg[oidx] = P;
    Ssum[oidx] = ls[ty * 4 + 0][c] + ls[ty * 4 + 1][c] + ls[ty * 4 + 2][c] + ls[ty * 4 + 3][c];
    Ssq[oidx]  = lq[ty * 4 + 0][c] + lq[ty * 4 + 1][c] + lq[ty * 4 + 2][c] + lq[ty * 4 + 3][c];
  }
}

// ================= kernel 2: scanB (8 blocks, 4 b-rows per block) =================
__global__ void __launch_bounds__(256) k_scanB(
    const float* __restrict__ x, const float* __restrict__ alpha,
    const float* __restrict__ rev_w, const float* __restrict__ rev_b,
    const float* __restrict__ Pseg, const float* __restrict__ Ssum, const float* __restrict__ Ssq,
    float* __restrict__ mean, float* __restrict__ rstd, float* __restrict__ stdv,
    float* __restrict__ CarryIn) {
  int b = blockIdx.x * 4 + (threadIdx.x >> 6), c = threadIdx.x & 63;
  float sm = 0.f, sq = 0.f;
#pragma unroll 8
  for (int s = 0; s < 64; ++s) {
    int idx = (b * 64 + s) * 64 + c;
    sm += Ssum[idx]; sq += Ssq[idx];
  }
  float mn = sm * (1.f / 4096.f);
  float var = sq * (1.f / 4096.f) - mn * mn;
  float sd = sqrtf(var + EPSf);
  float rs = 1.f / sd;
  mean[b * 64 + c] = mn; stdv[b * 64 + c] = sd; rstd[b * 64 + c] = rs;

  float w = rev_w[c], rb = rev_b[c];
  float g = rs * w, d = rb - mn * g;         // xn = g*x + d
  float a = sigm(alpha[c]);
  float a2 = a * a, a4 = a2 * a2, a8 = a4 * a4, a16 = a8 * a8, a32 = a16 * a16;
  float a64 = a32 * a32;
  float dk1s = d * (1.f - a64);
  float carry = fmaf(g, x[((size_t)b * Ln) * Cn + c], d);   // xn[0]
  for (int so = 0; so < 8; ++so) {
    float pv[8];
#pragma unroll
    for (int i = 0; i < 8; ++i)
      pv[i] = Pseg[((size_t)(b * 64 + so * 8 + i)) * 64 + c];
#pragma unroll
    for (int i = 0; i < 8; ++i) {
      CarryIn[((size_t)(b * 64 + so * 8 + i)) * 64 + c] = carry;
      carry = fmaf(a64, carry, fmaf(g, pv[i], dk1s));
    }
  }
}

// ---------------- kernel 3c: apply scan, write FRAGMENT-MAJOR bf16 via wave-local LDS stage ----
__global__ void __launch_bounds__(256) k_scanC(const float* __restrict__ x, const float* __restrict__ alpha,
                                               const float* __restrict__ rev_w, const float* __restrict__ rev_b,
                                               const float* __restrict__ mean, const float* __restrict__ rstd,
                                               const float* __restrict__ CarryIn, const float* __restrict__ Psub,
                                               bf16_t* __restrict__ Zt) {
  int b = blockIdx.x, ty = threadIdx.y, s = blockIdx.y * 4 + ty, t = threadIdx.x;
  int c4 = (t & 15) * 4, sub = t >> 4;
  float g[4], d[4], a[4], k1[4], a16[4], dk[4], tr[4];
#pragma unroll
  for (int i = 0; i < 4; ++i) {
    int c = c4 + i;
    float rs = rstd[b * 64 + c];
    g[i] = rs * rev_w[c]; d[i] = rev_b[c] - mean[b * 64 + c] * g[i];
    a[i] = sigm(alpha[c]); k1[i] = 1.f - a[i];
    float v = a[i] * a[i]; v *= v; v *= v; v *= v;
    a16[i] = v;
    dk[i] = d[i] * (1.f - v);
  }
  f32x4 cs = *reinterpret_cast<const f32x4*>(&CarryIn[((size_t)b * 64 + s) * 64 + c4]);
#pragma unroll
  for (int i = 0; i < 4; ++i) tr[i] = cs[i];
  for (int k = 0; k < sub; ++k) {            // compose prior subs (<=3 iters, masked)
    f32x4 p = *reinterpret_cast<const f32x4*>(&Psub[(((size_t)b * 64 + s) * 4 + k) * 64 + c4]);
#pragma unroll
    for (int i = 0; i < 4; ++i) tr[i] = fmaf(a16[i], tr[i], fmaf(g[i], p[i], dk[i]));
  }
  const float* xb = x + ((size_t)b * Ln + s * 64 + sub * 16) * Cn + c4;
  bf16x8 vs[4][2], vt[4][2];
#pragma unroll
  for (int j = 0; j < 16; ++j) {
    f32x4 v = *reinterpret_cast<const f32x4*>(xb + (size_t)j * Cn);
#pragma unroll
    for (int i = 0; i < 4; ++i) {
      float xn = fmaf(g[i], v[i], d[i]);
      tr[i] = fmaf(a[i], tr[i], k1[i] * xn);
      vs[i][j >> 3][j & 7] = f2bf(xn - tr[i]);
      vt[i][j >> 3][j & 7] = f2bf(tr[i]);
    }
  }
  // ---- fragment-major emit via LDS staging (per-wave, no cross-wave sharing) ----
  __shared__ short stage[4][8][520];         // 4 waves x 8 units x (512 + 8 pad) shorts = 33.3 KB
  short* BF0 = (short*)Zt;                   // path 0: seasonal
  const size_t PATH = (size_t)Bn * Cn * Ln;  // shorts per path
  int cq = (t & 15) >> 2;                    // unit n-part within wave
  int u = cq * 2 + (sub >> 1);               // unit index 0..7
  int hb = (sub & 1) * 2;                    // hi base {0, 2}
  // pass 1: seasonal
#pragma unroll
  for (int i = 0; i < 4; ++i) {
    int frv = (c4 & 15) + i;
    *reinterpret_cast<bf16x8*>(&stage[ty][u][(hb * 16 + frv) * 8]) = vs[i][0];
    *reinterpret_cast<bf16x8*>(&stage[ty][u][((hb + 1) * 16 + frv) * 8]) = vs[i][1];
  }
#pragma unroll
  for (int uu = 0; uu < 8; ++uu) {
    size_t nt = (size_t)b * 4 + (uu >> 1), ktg = (size_t)s * 2 + (uu & 1);
    *reinterpret_cast<bf16x8*>(BF0 + ((nt * 128 + ktg) << 9) + ((size_t)t << 3)) =
        *reinterpret_cast<const bf16x8*>(&stage[ty][uu][t * 8]);
  }
  // pass 2: trend (reuse buffer; wave-local ordering via lgkmcnt, no barrier needed)
#pragma unroll
  for (int i = 0; i < 4; ++i) {
    int frv = (c4 & 15) + i;
    *reinterpret_cast<bf16x8*>(&stage[ty][u][(hb * 16 + frv) * 8]) = vt[i][0];
    *reinterpret_cast<bf16x8*>(&stage[ty][u][((hb + 1) * 16 + frv) * 8]) = vt[i][1];
  }
#pragma unroll
  for (int uu = 0; uu < 8; ++uu) {
    size_t nt = (size_t)b * 4 + (uu >> 1), ktg = (size_t)s * 2 + (uu & 1);
    *reinterpret_cast<bf16x8*>(BF0 + PATH + ((nt * 128 + ktg) << 9) + ((size_t)t << 3)) =
        *reinterpret_cast<const bf16x8*>(&stage[ty][uu][t * 8]);
  }
}

// ---------------- kernel 5 (fused): gemm(NG) | prep(2) | S-reduce(6) ----------------
// prep + S-reduce are independent of gemm, needed only by k_epi -> hide under gemm.
template <int KS>
__global__ void __launch_bounds__(256, 3) k_gemm(
    const bf16_t* __restrict__ Wt, const bf16_t* __restrict__ Zt, float* __restrict__ Osr,
    const float* __restrict__ se_w, const float* __restrict__ sp_w,
    const float* __restrict__ se_b, const float* __restrict__ sp_b,
    const float* __restrict__ te_w, const float* __restrict__ tp_w,
    const float* __restrict__ te_b, const float* __restrict__ tp_b,
    const float* __restrict__ Spart,
    float* __restrict__ M, float* __restrict__ cvec, float* __restrict__ S) {
  constexpr int NG = (KS == 4) ? 768 : 192;
  __shared__ __align__(16) char smem[35072];
  int bid = blockIdx.x, t = threadIdx.x;

  if (bid >= NG) {
    int xb = bid - NG;
    if (xb < 2) {
      // ---------------- prep: fold the two 64->512->64 MLPs ----------------
      float (*ews)[68] = (float(*)[68])smem;
      float (*pws)[68] = (float(*)[68])(smem + 17408);
      float* ebs = (float*)(smem + 34816);
      int p = xb;
      const float* ew = p ? te_w : se_w;   // (64,512)
      const float* pw = p ? tp_w : sp_w;   // (512,64)
      const float* eb = p ? te_b : se_b;   // (512,)
      const float* pb = p ? tp_b : sp_b;   // (64,)
      int r0 = (t >> 4) * 4, c0 = (t & 15) * 4;
      float acc[4][4];
#pragma unroll
      for (int i = 0; i < 4; ++i)
#pragma unroll
        for (int j = 0; j < 4; ++j) acc[i][j] = 0.f;
      float cv = 0.f;
      for (int dc = 0; dc < 8; ++dc) {
        int d0 = dc * 64;
#pragma unroll
        for (int q = 0; q < 4; ++q) {
          int fi = t * 4 + q;
          int r = fi >> 4, dd = (fi * 4) & 63;
          *reinterpret_cast<f32x4*>(&ews[r][dd]) = *reinterpret_cast<const f32x4*>(&ew[r * 512 + d0 + dd]);
          *reinterpret_cast<f32x4*>(&pws[r][dd]) = *reinterpret_cast<const f32x4*>(&pw[(d0 + r) * 64 + dd]);
        }
        if (t < 64) ebs[t] = eb[d0 + t];
        __syncthreads();
#pragma unroll 4
        for (int g = 0; g < 16; ++g) {
          int dd = g * 4;
          f32x4 av[4], bv[4];
#pragma unroll
          for (int i = 0; i < 4; ++i) av[i] = *reinterpret_cast<const f32x4*>(&ews[r0 + i][dd]);
#pragma unroll
          for (int d = 0; d < 4; ++d) bv[d] = *reinterpret_cast<const f32x4*>(&pws[dd + d][c0]);
#pragma unroll
          for (int d = 0; d < 4; ++d)
#pragma unroll
            for (int i = 0; i < 4; ++i)
#pragma unroll
              for (int j = 0; j < 4; ++j) acc[i][j] = fmaf(av[i][d], bv[d][j], acc[i][j]);
        }
        if (t < 64) {
#pragma unroll 8
          for (int dd = 0; dd < 64; ++dd) cv = fmaf(ebs[dd], pws[dd][t], cv);
        }
        __syncthreads();
      }
#pragma unroll
      for (int i = 0; i < 4; ++i)
#pragma unroll
        for (int j = 0; j < 4; ++j)
          M[p * 4096 + (r0 + i) * 64 + c0 + j] = acc[i][j];
      if (t < 64) cvec[p * 64 + t] = cv + pb[t];
    } else {
      // ---------------- S-reduce: S[p][h] = sum_lc Spart[p][lc][h] ----------------
      int idx = (xb - 2) * 256 + t;              // 0..1535
      int p = idx / 768, h = idx % 768;
      float s = 0.f;
#pragma unroll 8
      for (int lc = 0; lc < 64; ++lc)
        s += Spart[((size_t)p * 64 + lc) * 768 + h];
      S[p * 768 + h] = s;
    }
    return;
  }

  // ---------------- gemm: LDS-free, fragment-major operands, lockstep barrier ----------------
  constexpr int per = NG >> 3;
  int swz = (bid & 7) * per + (bid >> 3);
  int z = swz / 96, rem = swz % 96;                   // 96 = 16 x-blocks * 6 y-blocks
  int by = rem >> 4, bx = rem & 15;
  int p = z / KS, kq = z % KS;
  const short* AF = (const short*)Wt + (size_t)p * HPn * Ln;
  const short* BF = (const short*)Zt + (size_t)p * (Bn * Cn) * Ln;
  int h0 = by * 128, n0 = bx * 128;
  int kbase = kq * (Ln / KS);
  const int NT = (Ln / KS) / 32;                      // K-steps of 32 (even)
  int wid = t >> 6, lane = t & 63;
  int wr = wid >> 1, wc = wid & 1;
  int fr = lane & 15, hi = lane >> 4;
  const short* ab = AF + ((((size_t)(h0 >> 4) + wr * 4) * 128 + (kbase >> 5)) << 9) + ((size_t)lane << 3);
  const short* bb = BF + ((((size_t)(n0 >> 4) + wc * 4) * 128 + (kbase >> 5)) << 9) + ((size_t)lane << 3);

  f32x4 acc[4][4];
#pragma unroll
  for (int i = 0; i < 4; ++i)
#pragma unroll
    for (int j = 0; j < 4; ++j) acc[i][j] = (f32x4){0.f, 0.f, 0.f, 0.f};

  auto LOAD = [&](bf16x8 (&a)[4], bf16x8 (&b)[4], int kt) {
#pragma unroll
    for (int i = 0; i < 4; ++i)
      a[i] = *reinterpret_cast<const bf16x8*>(ab + (((size_t)i * 128 + kt) << 9));
#pragma unroll
    for (int j = 0; j < 4; ++j)
      b[j] = *reinterpret_cast<const bf16x8*>(bb + (((size_t)j * 128 + kt) << 9));
  };
  auto COMPUTE = [&](const bf16x8 (&a)[4], const bf16x8 (&b)[4]) {
    __builtin_amdgcn_s_setprio(1);
#pragma unroll
    for (int i = 0; i < 4; ++i)
#pragma unroll
      for (int j = 0; j < 4; ++j)
        acc[i][j] = __builtin_amdgcn_mfma_f32_16x16x32_bf16(a[i], b[j], acc[i][j], 0, 0, 0);
    __builtin_amdgcn_s_setprio(0);
  };

  bf16x8 aA[4], bA[4], aB[4], bB[4];                  // named double buffers (rule #20)
  LOAD(aA, bA, 0);
  for (int tt = 0; tt < NT; tt += 2) {
    if (tt + 1 < NT) LOAD(aB, bB, tt + 1);
    __builtin_amdgcn_s_barrier();                     // lockstep: align waves' load windows
    COMPUTE(aA, bA);
    if (tt + 2 < NT) LOAD(aA, bA, tt + 2);
    __builtin_amdgcn_s_barrier();
    if (tt + 1 < NT) COMPUTE(aB, bB);
  }

#pragma unroll
  for (int i = 0; i < 4; ++i) {
#pragma unroll
    for (int j = 0; j < 4; ++j) {
#pragma unroll
      for (int r = 0; r < 4; ++r) {
        int m = wr * 64 + i * 16 + hi * 4 + r;
        int h = h0 + m;
        if (h < Hn) {
          int n = n0 + wc * 64 + j * 16 + fr;
          int bidx = n >> 6, c = n & 63;
          Osr[(((size_t)z * Bn + bidx) * Hn + h) * Cn + c] = acc[i][j][r];
        }
      }
    }
  }
}

// ---------------- kernel 6: epilogue — 32 rows/block, cp-quad f32x4 broadcast reads ----------
template <int KS>
__global__ void __launch_bounds__(256) k_epi(const float* __restrict__ Osr, const float* __restrict__ M,
                                             const float* __restrict__ cvec, const float* __restrict__ S,
                                             const float* __restrict__ st_b, const float* __restrict__ tt_b,
                                             const float* __restrict__ rev_w, const float* __restrict__ rev_b,
                                             const float* __restrict__ mean, const float* __restrict__ stdv,
                                             float* __restrict__ out) {
  __shared__ float Msh[2][64][64];    // 32 KB
  __shared__ float rowS[32][64];      // 8 KB
  __shared__ float rowT[32][64];      // 8 KB
  int t = threadIdx.x;
  for (int i = t; i < 2048; i += 256)   // vectorized Msh stage (8 x b128 per thread)
    reinterpret_cast<f32x4*>(Msh)[i] = reinterpret_cast<const f32x4*>(M)[i];
  int c = t & 63, grp = t >> 6;       // grp 0..3, 8 rows each
  float w = rev_w[c], rb = rev_b[c];
  float cs = cvec[c], ct = cvec[64 + c];
  int base = blockIdx.x * 32;
#pragma unroll
  for (int k = 0; k < 8; ++k) {
    int rl = grp * 8 + k;
    int r = base + rl;
    int b = r / 720, h = r % 720;
    float vs = 0.f, vt = 0.f;
#pragma unroll
    for (int kq = 0; kq < KS; ++kq) {
      vs += Osr[(((size_t)kq * Bn + b) * Hn + h) * Cn + c];
      vt += Osr[(((size_t)(KS + kq) * Bn + b) * Hn + h) * Cn + c];
    }
    rowS[rl][c] = vs;
    rowT[rl][c] = vt;
  }
  __syncthreads();
  float acc[8];
  int hh[8], bb[8];
#pragma unroll
  for (int k = 0; k < 8; ++k) {
    int r = base + grp * 8 + k;
    bb[k] = r / 720; hh[k] = r % 720;
    acc[k] = cs * S[hh[k]] + ct * S[768 + hh[k]] + st_b[hh[k]] + tt_b[hh[k]];
  }
  int r0 = grp * 8;
  for (int cq = 0; cq < 16; ++cq) {
    f32x4 rs[8], rt[8];
#pragma unroll
    for (int k = 0; k < 8; ++k) rs[k] = *reinterpret_cast<const f32x4*>(&rowS[r0 + k][cq * 4]);
#pragma unroll
    for (int k = 0; k < 8; ++k) rt[k] = *reinterpret_cast<const f32x4*>(&rowT[r0 + k][cq * 4]);
#pragma unroll
    for (int i = 0; i < 4; ++i) {
      float m0 = Msh[0][cq * 4 + i][c], m1 = Msh[1][cq * 4 + i][c];
#pragma unroll
      for (int k = 0; k < 8; ++k)
        acc[k] = fmaf(rs[k][i], m0, fmaf(rt[k][i], m1, acc[k]));
    }
  }
  float winv = 1.f / (w + EPSf);
#pragma unroll
  for (int k = 0; k < 8; ++k) {
    float o = (acc[k] - rb) * winv * stdv[bb[k] * Cn + c] + mean[bb[k] * Cn + c];
    out[(size_t)(base + r0 + k) * 64 + c] = o;
  }
}

// ---------------- launch ----------------
extern "C" void kernel_launch(void* const* d_in, const int* in_sizes, int n_in,
                              void* d_out, int out_size, void* d_ws, size_t ws_size,
                              hipStream_t stream) {
  const float* x     = (const float*)d_in[0];
  const float* alpha = (const float*)d_in[1];
  const float* rev_w = (const float*)d_in[2];
  const float* rev_b = (const float*)d_in[3];
  const float* se_w  = (const float*)d_in[4];
  const float* se_b  = (const float*)d_in[5];
  const float* sp_w  = (const float*)d_in[6];
  const float* sp_b  = (const float*)d_in[7];
  const float* st_w  = (const float*)d_in[8];
  const float* st_b  = (const float*)d_in[9];
  const float* te_w  = (const float*)d_in[10];
  const float* te_b  = (const float*)d_in[11];
  const float* tp_w  = (const float*)d_in[12];
  const float* tp_b  = (const float*)d_in[13];
  const float* tt_w  = (const float*)d_in[14];
  const float* tt_b  = (const float*)d_in[15];
  float* out = (float*)d_out;

  const size_t SZ_WT  = (size_t)2 * HPn * Ln * 2;          // 12.58 MB (fragment-major AF)
  const size_t SZ_ZT  = (size_t)2 * Bn * Cn * Ln * 2;      // 33.55 MB (fragment-major BF)
  const size_t SZ_SEG = (size_t)Bn * 64 * 64 * 4;          // 0.5 MB seg-level scratch
  const size_t SZ_M   = 2 * 64 * 64 * 4;                   // 32 KB
  const size_t SZ_CV  = 2 * 64 * 4;
  const size_t SZ_S   = 2 * 768 * 4;
  const size_t SZ_SP  = (size_t)2 * 64 * 768 * 4;          // Spart 393 KB
  const size_t TAIL   = SZ_M + SZ_CV + SZ_S + SZ_SP + 3 * (size_t)Bn * Cn * 4;

  const size_t NEED4 = SZ_WT + SZ_ZT + 8 * OSR_SLICE * 4 + TAIL;
  const int KS = (ws_size >= NEED4) ? 4 : 1;
  const size_t SZ_OSR = (size_t)(2 * KS) * OSR_SLICE * 4;

  char* ws = (char*)d_ws;
  bf16_t* Wt   = (bf16_t*)(ws);
  bf16_t* Zt   = (bf16_t*)(ws + SZ_WT);
  float*  Osr  = (float*)(ws + SZ_WT + SZ_ZT);
  // scan scratch aliases Osr (dead before k_gemm writes Osr)
  float*  Psub  = Osr;                                     // 2 MB
  float*  Pseg  = (float*)((char*)Psub + 4 * SZ_SEG);
  float*  Ssum  = (float*)((char*)Pseg + SZ_SEG);
  float*  Ssq   = (float*)((char*)Ssum + SZ_SEG);
  float*  Carry = (float*)((char*)Ssq + SZ_SEG);
  char* tail = ws + SZ_WT + SZ_ZT + SZ_OSR;
  float* Mbuf = (float*)tail;                 tail += SZ_M;
  float* cvec = (float*)tail;                 tail += SZ_CV;
  float* S    = (float*)tail;                 tail += SZ_S;
  float* Spart = (float*)tail;                tail += SZ_SP;
  float* mean = (float*)tail;                 tail += (size_t)Bn * Cn * 4;
  float* rstd = (float*)tail;                 tail += (size_t)Bn * Cn * 4;
  float* stdv = (float*)tail;

  k_preA<<<2048, 256, 0, stream>>>(st_w, tt_w, x, alpha, Wt, Spart, Psub, Pseg, Ssum, Ssq);
  k_scanB<<<8, 256, 0, stream>>>(x, alpha, rev_w, rev_b, Pseg, Ssum, Ssq, mean, rstd, stdv, Carry);
  k_scanC<<<dim3(32, 16), dim3(64, 4), 0, stream>>>(x, alpha, rev_w, rev_b, mean, rstd, Carry, Psub, Zt);
  if (KS == 4) {
    k_gemm<4><<<776, 256, 0, stream>>>(Wt, Zt, Osr, se_w, sp_w, se_b, sp_b, te_w, tp_w, te_b, tp_b,
                                       Spart, Mbuf, cvec, S);
    k_epi<4><<<720, 256, 0, stream>>>(Osr, Mbuf, cvec, S, st_b, tt_b, rev_w, rev_b, mean, stdv, out);
  } else {
    k_gemm<1><<<200, 256, 0, stream>>>(Wt, Zt, Osr, se_w, sp_w, se_b, sp_b, te_w, tp_w, te_b, tp_b,
                                       Spart, Mbuf, cvec, S);
    k_epi<1><<<720, 256, 0, stream>>>(Osr, Mbuf, cvec, S, st_b, tt_b, rev_w, rev_b, mean, stdv, out);
  }
}

// Round 15
// 109.074 us; speedup vs baseline: 1.0043x; 1.0043x over previous
//
#include <hip/hip_runtime.h>
#include <hip/hip_bf16.h>
#include <string.h>
#include <stdint.h>

typedef __hip_bfloat16 bf16_t;
typedef float f32x4 __attribute__((ext_vector_type(4)));
typedef short bf16x8 __attribute__((ext_vector_type(8)));

static constexpr int Bn = 32, Ln = 4096, Cn = 64, Hn = 720, HPn = 768;
static constexpr float EPSf = 1e-5f;

static constexpr size_t OSR_SLICE = (size_t)Bn * Hn * Cn;   // f32 elements per K-slice per path

__device__ __forceinline__ short f2bf(float f) {
  bf16_t h = __float2bfloat16(f);
  unsigned short u; memcpy(&u, &h, 2);
  return (short)u;
}

__device__ __forceinline__ float sigm(float v) { return 1.f / (1.f + expf(-v)); }

// ================= kernel 1 (fused): wprep(1536, f32x4 reads) | scanA(512) =================
__global__ void __launch_bounds__(256) k_preA(
    const float* __restrict__ st_w, const float* __restrict__ tt_w,
    const float* __restrict__ x, const float* __restrict__ alpha,
    bf16_t* __restrict__ Wt, float* __restrict__ Spart,
    float* __restrict__ Psub, float* __restrict__ Pseg,
    float* __restrict__ Ssum, float* __restrict__ Ssq) {
  __shared__ __align__(16) char smem[20736];
  int bid = blockIdx.x, t = threadIdx.x;

  if (bid < 1536) {
    // -------- wprep: tw -> fragment-major AF (+Spart colsum partials), f32x4 global reads ------
    float (*tile)[65] = (float(*)[65])smem;             // 16640 B (pad 65: conflict-free emit)
    float (*cs16)[64] = (float(*)[64])(smem + 16640);   // 4096 B
    int p = bid / 768, rem = bid % 768;
    int lc = rem & 63, hc = rem >> 6;
    const float* W = p ? tt_w : st_w;                   // (4096, 720)
    int l0 = lc * 64, h0 = hc * 64;
    int g16 = t >> 4, c4l = (t & 15) * 4;
    int h = h0 + c4l;
    f32x4 ps = (f32x4){0.f, 0.f, 0.f, 0.f};
#pragma unroll
    for (int rr = 0; rr < 4; ++rr) {
      int r = rr * 16 + g16;
      const float* src = &W[(size_t)(l0 + r) * Hn + h];
      f32x4 v;
      if (h + 3 < Hn) {
        v = *reinterpret_cast<const f32x4*>(src);
      } else {
#pragma unroll
        for (int i = 0; i < 4; ++i) v[i] = (h + i < Hn) ? src[i] : 0.f;
      }
      tile[r][c4l + 0] = v[0]; tile[r][c4l + 1] = v[1];
      tile[r][c4l + 2] = v[2]; tile[r][c4l + 3] = v[3];
      ps += v;
    }
    *reinterpret_cast<f32x4*>(&cs16[g16][c4l]) = ps;
    __syncthreads();
    if (t < 64) {
      float s = 0.f;
#pragma unroll
      for (int g = 0; g < 16; ++g) s += cs16[g][t];
      Spart[((size_t)p * 64 + lc) * 768 + h0 + t] = s;
    }
    short* AF = (short*)Wt + (size_t)p * HPn * Ln;
#pragma unroll
    for (int u = 0; u < 2; ++u) {
      int uid = u * 256 + t;
      int ln = uid & 63, ktl = (uid >> 6) & 1, htl = uid >> 7;
      int fr = ln & 15, hi = ln >> 4;
      int ll = ktl * 32 + hi * 8;
      int hh = htl * 16 + fr;
      bf16x8 v;
#pragma unroll
      for (int e = 0; e < 8; ++e) v[e] = f2bf(tile[ll + e][hh]);
      size_t ht = (size_t)(h0 >> 4) + htl, ktg = (size_t)(l0 >> 5) + ktl;
      *reinterpret_cast<bf16x8*>(&AF[((ht * 128 + ktg) << 9) + ((size_t)ln << 3)]) = v;
    }
  } else {
    // ---------------- scanA: (c-quad x l-sub16) raw-x partials + seg reduce ----------------
    float (*lp)[64] = (float(*)[64])smem;
    float (*ls)[64] = (float(*)[64])(smem + 4096);
    float (*lq)[64] = (float(*)[64])(smem + 8192);
    int idx = bid - 1536;
    int b = idx >> 4, sg = idx & 15;
    int ty = t >> 6, tx = t & 63;
    int s = sg * 4 + ty;
    int c4 = (tx & 15) * 4, sub = tx >> 4;
    float a[4], k1[4];
#pragma unroll
    for (int i = 0; i < 4; ++i) { a[i] = sigm(alpha[c4 + i]); k1[i] = 1.f - a[i]; }
    const float* xb = x + ((size_t)b * Ln + s * 64 + sub * 16) * Cn + c4;
    float pr[4] = {0.f, 0.f, 0.f, 0.f}, sm[4] = {0.f, 0.f, 0.f, 0.f}, sq[4] = {0.f, 0.f, 0.f, 0.f};
#pragma unroll
    for (int j = 0; j < 16; ++j) {
      f32x4 v = *reinterpret_cast<const f32x4*>(xb + (size_t)j * Cn);
#pragma unroll
      for (int i = 0; i < 4; ++i) {
        sm[i] += v[i];
        sq[i] = fmaf(v[i], v[i], sq[i]);
        pr[i] = fmaf(a[i], pr[i], k1[i] * v[i]);
      }
    }
    *reinterpret_cast<f32x4*>(&Psub[(((size_t)b * 64 + s) * 4 + sub) * 64 + c4]) =
        (f32x4){pr[0], pr[1], pr[2], pr[3]};
#pragma unroll
    for (int i = 0; i < 4; ++i) {
      lp[ty * 4 + sub][c4 + i] = pr[i];
      ls[ty * 4 + sub][c4 + i] = sm[i];
      lq[ty * 4 + sub][c4 + i] = sq[i];
    }
    __syncthreads();
    int c = tx;
    float av = sigm(alpha[c]);
    float a16 = av * av; a16 *= a16; a16 *= a16; a16 *= a16;   // a^16
    float P = ((lp[ty * 4 + 0][c] * a16 + lp[ty * 4 + 1][c]) * a16 + lp[ty * 4 + 2][c]) * a16 + lp[ty * 4 + 3][c];
    int oidx = (b * 64 + s) * 64 + c;
    Pseg[oidx] = P;
    Ssum[oidx] = ls[ty * 4 + 0][c] + ls[ty * 4 + 1][c] + ls[ty * 4 + 2][c] + ls[ty * 4 + 3][c];
    Ssq[oidx]  = lq[ty * 4 + 0][c] + lq[ty * 4 + 1][c] + lq[ty * 4 + 2][c] + lq[ty * 4 + 3][c];
  }
}

// ====== kernel 2 (fused, 16 blocks): scanB(8) | prep(2) | S-reduce(6) ======
// All small latency-bound pieces share one dispatch; 35KB LDS only gates these 16 blocks.
__global__ void __launch_bounds__(256) k_mid(
    const float* __restrict__ x, const float* __restrict__ alpha,
    const float* __restrict__ rev_w, const float* __restrict__ rev_b,
    const float* __restrict__ Pseg, const float* __restrict__ Ssum, const float* __restrict__ Ssq,
    const float* __restrict__ se_w, const float* __restrict__ sp_w,
    const float* __restrict__ se_b, const float* __restrict__ sp_b,
    const float* __restrict__ te_w, const float* __restrict__ tp_w,
    const float* __restrict__ te_b, const float* __restrict__ tp_b,
    const float* __restrict__ Spart,
    float* __restrict__ mean, float* __restrict__ rstd, float* __restrict__ stdv,
    float* __restrict__ CarryIn, float* __restrict__ M, float* __restrict__ cvec,
    float* __restrict__ S) {
  __shared__ __align__(16) char smem[35072];
  int bid = blockIdx.x, t = threadIdx.x;

  if (bid < 8) {
    // ---------------- scanB: stats finalize + 64-step carry scan ----------------
    int b = bid * 4 + (t >> 6), c = t & 63;
    float sm = 0.f, sq = 0.f;
#pragma unroll 8
    for (int s = 0; s < 64; ++s) {
      int idx = (b * 64 + s) * 64 + c;
      sm += Ssum[idx]; sq += Ssq[idx];
    }
    float mn = sm * (1.f / 4096.f);
    float var = sq * (1.f / 4096.f) - mn * mn;
    float sd = sqrtf(var + EPSf);
    float rs = 1.f / sd;
    mean[b * 64 + c] = mn; stdv[b * 64 + c] = sd; rstd[b * 64 + c] = rs;

    float w = rev_w[c], rb = rev_b[c];
    float g = rs * w, d = rb - mn * g;         // xn = g*x + d
    float a = sigm(alpha[c]);
    float a2 = a * a, a4 = a2 * a2, a8 = a4 * a4, a16 = a8 * a8, a32 = a16 * a16;
    float a64 = a32 * a32;
    float dk1s = d * (1.f - a64);
    float carry = fmaf(g, x[((size_t)b * Ln) * Cn + c], d);   // xn[0]
    for (int so = 0; so < 8; ++so) {
      float pv[8];
#pragma unroll
      for (int i = 0; i < 8; ++i)
        pv[i] = Pseg[((size_t)(b * 64 + so * 8 + i)) * 64 + c];
#pragma unroll
      for (int i = 0; i < 8; ++i) {
        CarryIn[((size_t)(b * 64 + so * 8 + i)) * 64 + c] = carry;
        carry = fmaf(a64, carry, fmaf(g, pv[i], dk1s));
      }
    }
  } else if (bid < 10) {
    // ---------------- prep: fold the two 64->512->64 MLPs ----------------
    float (*ews)[68] = (float(*)[68])smem;
    float (*pws)[68] = (float(*)[68])(smem + 17408);
    float* ebs = (float*)(smem + 34816);
    int p = bid - 8;
    const float* ew = p ? te_w : se_w;   // (64,512)
    const float* pw = p ? tp_w : sp_w;   // (512,64)
    const float* eb = p ? te_b : se_b;   // (512,)
    const float* pb = p ? tp_b : sp_b;   // (64,)
    int r0 = (t >> 4) * 4, c0 = (t & 15) * 4;
    float acc[4][4];
#pragma unroll
    for (int i = 0; i < 4; ++i)
#pragma unroll
      for (int j = 0; j < 4; ++j) acc[i][j] = 0.f;
    float cv = 0.f;
    for (int dc = 0; dc < 8; ++dc) {
      int d0 = dc * 64;
#pragma unroll
      for (int q = 0; q < 4; ++q) {
        int fi = t * 4 + q;
        int r = fi >> 4, dd = (fi * 4) & 63;
        *reinterpret_cast<f32x4*>(&ews[r][dd]) = *reinterpret_cast<const f32x4*>(&ew[r * 512 + d0 + dd]);
        *reinterpret_cast<f32x4*>(&pws[r][dd]) = *reinterpret_cast<const f32x4*>(&pw[(d0 + r) * 64 + dd]);
      }
      if (t < 64) ebs[t] = eb[d0 + t];
      __syncthreads();
#pragma unroll 4
      for (int g = 0; g < 16; ++g) {
        int dd = g * 4;
        f32x4 av[4], bv[4];
#pragma unroll
        for (int i = 0; i < 4; ++i) av[i] = *reinterpret_cast<const f32x4*>(&ews[r0 + i][dd]);
#pragma unroll
        for (int d = 0; d < 4; ++d) bv[d] = *reinterpret_cast<const f32x4*>(&pws[dd + d][c0]);
#pragma unroll
        for (int d = 0; d < 4; ++d)
#pragma unroll
          for (int i = 0; i < 4; ++i)
#pragma unroll
            for (int j = 0; j < 4; ++j) acc[i][j] = fmaf(av[i][d], bv[d][j], acc[i][j]);
      }
      if (t < 64) {
#pragma unroll 8
        for (int dd = 0; dd < 64; ++dd) cv = fmaf(ebs[dd], pws[dd][t], cv);
      }
      __syncthreads();
    }
#pragma unroll
    for (int i = 0; i < 4; ++i)
#pragma unroll
      for (int j = 0; j < 4; ++j)
        M[p * 4096 + (r0 + i) * 64 + c0 + j] = acc[i][j];
    if (t < 64) cvec[p * 64 + t] = cv + pb[t];
  } else {
    // ---------------- S-reduce: S[p][h] = sum_lc Spart[p][lc][h] ----------------
    int idx = (bid - 10) * 256 + t;              // 0..1535
    int p = idx / 768, h = idx % 768;
    float s = 0.f;
#pragma unroll 8
    for (int lc = 0; lc < 64; ++lc)
      s += Spart[((size_t)p * 64 + lc) * 768 + h];
    S[p * 768 + h] = s;
  }
}

// ---------------- kernel 3c: apply scan, write FRAGMENT-MAJOR bf16 via wave-local LDS stage ----
__global__ void __launch_bounds__(256) k_scanC(const float* __restrict__ x, const float* __restrict__ alpha,
                                               const float* __restrict__ rev_w, const float* __restrict__ rev_b,
                                               const float* __restrict__ mean, const float* __restrict__ rstd,
                                               const float* __restrict__ CarryIn, const float* __restrict__ Psub,
                                               bf16_t* __restrict__ Zt) {
  int b = blockIdx.x, ty = threadIdx.y, s = blockIdx.y * 4 + ty, t = threadIdx.x;
  int c4 = (t & 15) * 4, sub = t >> 4;
  float g[4], d[4], a[4], k1[4], a16[4], dk[4], tr[4];
#pragma unroll
  for (int i = 0; i < 4; ++i) {
    int c = c4 + i;
    float rs = rstd[b * 64 + c];
    g[i] = rs * rev_w[c]; d[i] = rev_b[c] - mean[b * 64 + c] * g[i];
    a[i] = sigm(alpha[c]); k1[i] = 1.f - a[i];
    float v = a[i] * a[i]; v *= v; v *= v; v *= v;
    a16[i] = v;
    dk[i] = d[i] * (1.f - v);
  }
  f32x4 cs = *reinterpret_cast<const f32x4*>(&CarryIn[((size_t)b * 64 + s) * 64 + c4]);
#pragma unroll
  for (int i = 0; i < 4; ++i) tr[i] = cs[i];
  for (int k = 0; k < sub; ++k) {            // compose prior subs (<=3 iters, masked)
    f32x4 p = *reinterpret_cast<const f32x4*>(&Psub[(((size_t)b * 64 + s) * 4 + k) * 64 + c4]);
#pragma unroll
    for (int i = 0; i < 4; ++i) tr[i] = fmaf(a16[i], tr[i], fmaf(g[i], p[i], dk[i]));
  }
  const float* xb = x + ((size_t)b * Ln + s * 64 + sub * 16) * Cn + c4;
  bf16x8 vs[4][2], vt[4][2];
#pragma unroll
  for (int j = 0; j < 16; ++j) {
    f32x4 v = *reinterpret_cast<const f32x4*>(xb + (size_t)j * Cn);
#pragma unroll
    for (int i = 0; i < 4; ++i) {
      float xn = fmaf(g[i], v[i], d[i]);
      tr[i] = fmaf(a[i], tr[i], k1[i] * xn);
      vs[i][j >> 3][j & 7] = f2bf(xn - tr[i]);
      vt[i][j >> 3][j & 7] = f2bf(tr[i]);
    }
  }
  // ---- fragment-major emit via LDS staging (per-wave, no cross-wave sharing) ----
  __shared__ short stage[4][8][520];         // 4 waves x 8 units x (512 + 8 pad) shorts = 33.3 KB
  short* BF0 = (short*)Zt;                   // path 0: seasonal
  const size_t PATH = (size_t)Bn * Cn * Ln;  // shorts per path
  int cq = (t & 15) >> 2;                    // unit n-part within wave
  int u = cq * 2 + (sub >> 1);               // unit index 0..7
  int hb = (sub & 1) * 2;                    // hi base {0, 2}
  // pass 1: seasonal
#pragma unroll
  for (int i = 0; i < 4; ++i) {
    int frv = (c4 & 15) + i;
    *reinterpret_cast<bf16x8*>(&stage[ty][u][(hb * 16 + frv) * 8]) = vs[i][0];
    *reinterpret_cast<bf16x8*>(&stage[ty][u][((hb + 1) * 16 + frv) * 8]) = vs[i][1];
  }
#pragma unroll
  for (int uu = 0; uu < 8; ++uu) {
    size_t nt = (size_t)b * 4 + (uu >> 1), ktg = (size_t)s * 2 + (uu & 1);
    *reinterpret_cast<bf16x8*>(BF0 + ((nt * 128 + ktg) << 9) + ((size_t)t << 3)) =
        *reinterpret_cast<const bf16x8*>(&stage[ty][uu][t * 8]);
  }
  // pass 2: trend (reuse buffer; wave-local ordering via lgkmcnt, no barrier needed)
#pragma unroll
  for (int i = 0; i < 4; ++i) {
    int frv = (c4 & 15) + i;
    *reinterpret_cast<bf16x8*>(&stage[ty][u][(hb * 16 + frv) * 8]) = vt[i][0];
    *reinterpret_cast<bf16x8*>(&stage[ty][u][((hb + 1) * 16 + frv) * 8]) = vt[i][1];
  }
#pragma unroll
  for (int uu = 0; uu < 8; ++uu) {
    size_t nt = (size_t)b * 4 + (uu >> 1), ktg = (size_t)s * 2 + (uu & 1);
    *reinterpret_cast<bf16x8*>(BF0 + PATH + ((nt * 128 + ktg) << 9) + ((size_t)t << 3)) =
        *reinterpret_cast<const bf16x8*>(&stage[ty][uu][t * 8]);
  }
}

// ---------------- kernel 5: bf16 MFMA GEMM — LDS-FREE with per-K-step lockstep barrier ----------
// Both operands fragment-major in global. Standalone (NO smem!) — r12's measured 39 µs config.
template <int KS>
__global__ void __launch_bounds__(256, 3) k_gemm(const bf16_t* __restrict__ Wt, const bf16_t* __restrict__ Zt,
                                                 float* __restrict__ Osr) {
  // XCD-chunked bijective swizzle (gridDim.x % 8 == 0)
  int per = gridDim.x >> 3;
  int swz = (blockIdx.x & 7) * per + (blockIdx.x >> 3);
  int z = swz / 96, rem = swz % 96;                   // 96 = 16 x-blocks * 6 y-blocks
  int by = rem >> 4, bx = rem & 15;
  int p = z / KS, kq = z % KS;
  const short* AF = (const short*)Wt + (size_t)p * HPn * Ln;
  const short* BF = (const short*)Zt + (size_t)p * (Bn * Cn) * Ln;
  int h0 = by * 128, n0 = bx * 128;
  int kbase = kq * (Ln / KS);
  const int NT = (Ln / KS) / 32;                      // K-steps of 32 (even)
  int tid = threadIdx.x, wid = tid >> 6, lane = tid & 63;
  int wr = wid >> 1, wc = wid & 1;
  int fr = lane & 15, hi = lane >> 4;
  const short* ab = AF + ((((size_t)(h0 >> 4) + wr * 4) * 128 + (kbase >> 5)) << 9) + ((size_t)lane << 3);
  const short* bb = BF + ((((size_t)(n0 >> 4) + wc * 4) * 128 + (kbase >> 5)) << 9) + ((size_t)lane << 3);

  f32x4 acc[4][4];
#pragma unroll
  for (int i = 0; i < 4; ++i)
#pragma unroll
    for (int j = 0; j < 4; ++j) acc[i][j] = (f32x4){0.f, 0.f, 0.f, 0.f};

  auto LOAD = [&](bf16x8 (&a)[4], bf16x8 (&b)[4], int kt) {
#pragma unroll
    for (int i = 0; i < 4; ++i)
      a[i] = *reinterpret_cast<const bf16x8*>(ab + (((size_t)i * 128 + kt) << 9));
#pragma unroll
    for (int j = 0; j < 4; ++j)
      b[j] = *reinterpret_cast<const bf16x8*>(bb + (((size_t)j * 128 + kt) << 9));
  };
  auto COMPUTE = [&](const bf16x8 (&a)[4], const bf16x8 (&b)[4]) {
    __builtin_amdgcn_s_setprio(1);
#pragma unroll
    for (int i = 0; i < 4; ++i)
#pragma unroll
      for (int j = 0; j < 4; ++j)
        acc[i][j] = __builtin_amdgcn_mfma_f32_16x16x32_bf16(a[i], b[j], acc[i][j], 0, 0, 0);
    __builtin_amdgcn_s_setprio(0);
  };

  bf16x8 aA[4], bA[4], aB[4], bB[4];                  // named double buffers (rule #20)
  LOAD(aA, bA, 0);
  for (int t = 0; t < NT; t += 2) {
    if (t + 1 < NT) LOAD(aB, bB, t + 1);
    __builtin_amdgcn_s_barrier();                     // lockstep: align waves' load windows
    COMPUTE(aA, bA);
    if (t + 2 < NT) LOAD(aA, bA, t + 2);
    __builtin_amdgcn_s_barrier();
    if (t + 1 < NT) COMPUTE(aB, bB);
  }

#pragma unroll
  for (int i = 0; i < 4; ++i) {
#pragma unroll
    for (int j = 0; j < 4; ++j) {
#pragma unroll
      for (int r = 0; r < 4; ++r) {
        int m = wr * 64 + i * 16 + hi * 4 + r;
        int h = h0 + m;
        if (h < Hn) {
          int n = n0 + wc * 64 + j * 16 + fr;
          int bidx = n >> 6, c = n & 63;
          Osr[(((size_t)z * Bn + bidx) * Hn + h) * Cn + c] = acc[i][j][r];
        }
      }
    }
  }
}

// ---------------- kernel 6: epilogue — 32 rows/block, cp-quad f32x4 broadcast reads ----------
template <int KS>
__global__ void __launch_bounds__(256) k_epi(const float* __restrict__ Osr, const float* __restrict__ M,
                                             const float* __restrict__ cvec, const float* __restrict__ S,
                                             const float* __restrict__ st_b, const float* __restrict__ tt_b,
                                             const float* __restrict__ rev_w, const float* __restrict__ rev_b,
                                             const float* __restrict__ mean, const float* __restrict__ stdv,
                                             float* __restrict__ out) {
  __shared__ float Msh[2][64][64];    // 32 KB
  __shared__ float rowS[32][64];      // 8 KB
  __shared__ float rowT[32][64];      // 8 KB
  int t = threadIdx.x;
  for (int i = t; i < 2048; i += 256)   // vectorized Msh stage (8 x b128 per thread)
    reinterpret_cast<f32x4*>(Msh)[i] = reinterpret_cast<const f32x4*>(M)[i];
  int c = t & 63, grp = t >> 6;       // grp 0..3, 8 rows each
  float w = rev_w[c], rb = rev_b[c];
  float cs = cvec[c], ct = cvec[64 + c];
  int base = blockIdx.x * 32;
#pragma unroll
  for (int k = 0; k < 8; ++k) {
    int rl = grp * 8 + k;
    int r = base + rl;
    int b = r / 720, h = r % 720;
    float vs = 0.f, vt = 0.f;
#pragma unroll
    for (int kq = 0; kq < KS; ++kq) {
      vs += Osr[(((size_t)kq * Bn + b) * Hn + h) * Cn + c];
      vt += Osr[(((size_t)(KS + kq) * Bn + b) * Hn + h) * Cn + c];
    }
    rowS[rl][c] = vs;
    rowT[rl][c] = vt;
  }
  __syncthreads();
  float acc[8];
  int hh[8], bb[8];
#pragma unroll
  for (int k = 0; k < 8; ++k) {
    int r = base + grp * 8 + k;
    bb[k] = r / 720; hh[k] = r % 720;
    acc[k] = cs * S[hh[k]] + ct * S[768 + hh[k]] + st_b[hh[k]] + tt_b[hh[k]];
  }
  int r0 = grp * 8;
  for (int cq = 0; cq < 16; ++cq) {
    f32x4 rs[8], rt[8];
#pragma unroll
    for (int k = 0; k < 8; ++k) rs[k] = *reinterpret_cast<const f32x4*>(&rowS[r0 + k][cq * 4]);
#pragma unroll
    for (int k = 0; k < 8; ++k) rt[k] = *reinterpret_cast<const f32x4*>(&rowT[r0 + k][cq * 4]);
#pragma unroll
    for (int i = 0; i < 4; ++i) {
      float m0 = Msh[0][cq * 4 + i][c], m1 = Msh[1][cq * 4 + i][c];
#pragma unroll
      for (int k = 0; k < 8; ++k)
        acc[k] = fmaf(rs[k][i], m0, fmaf(rt[k][i], m1, acc[k]));
    }
  }
  float winv = 1.f / (w + EPSf);
#pragma unroll
  for (int k = 0; k < 8; ++k) {
    float o = (acc[k] - rb) * winv * stdv[bb[k] * Cn + c] + mean[bb[k] * Cn + c];
    out[(size_t)(base + r0 + k) * 64 + c] = o;
  }
}

// ---------------- launch ----------------
extern "C" void kernel_launch(void* const* d_in, const int* in_sizes, int n_in,
                              void* d_out, int out_size, void* d_ws, size_t ws_size,
                              hipStream_t stream) {
  const float* x     = (const float*)d_in[0];
  const float* alpha = (const float*)d_in[1];
  const float* rev_w = (const float*)d_in[2];
  const float* rev_b = (const float*)d_in[3];
  const float* se_w  = (const float*)d_in[4];
  const float* se_b  = (const float*)d_in[5];
  const float* sp_w  = (const float*)d_in[6];
  const float* sp_b  = (const float*)d_in[7];
  const float* st_w  = (const float*)d_in[8];
  const float* st_b  = (const float*)d_in[9];
  const float* te_w  = (const float*)d_in[10];
  const float* te_b  = (const float*)d_in[11];
  const float* tp_w  = (const float*)d_in[12];
  const float* tp_b  = (const float*)d_in[13];
  const float* tt_w  = (const float*)d_in[14];
  const float* tt_b  = (const float*)d_in[15];
  float* out = (float*)d_out;

  const size_t SZ_WT  = (size_t)2 * HPn * Ln * 2;          // 12.58 MB (fragment-major AF)
  const size_t SZ_ZT  = (size_t)2 * Bn * Cn * Ln * 2;      // 33.55 MB (fragment-major BF)
  const size_t SZ_SEG = (size_t)Bn * 64 * 64 * 4;          // 0.5 MB seg-level scratch
  const size_t SZ_M   = 2 * 64 * 64 * 4;                   // 32 KB
  const size_t SZ_CV  = 2 * 64 * 4;
  const size_t SZ_S   = 2 * 768 * 4;
  const size_t SZ_SP  = (size_t)2 * 64 * 768 * 4;          // Spart 393 KB
  const size_t TAIL   = SZ_M + SZ_CV + SZ_S + SZ_SP + 3 * (size_t)Bn * Cn * 4;

  const size_t NEED4 = SZ_WT + SZ_ZT + 8 * OSR_SLICE * 4 + TAIL;
  const int KS = (ws_size >= NEED4) ? 4 : 1;
  const size_t SZ_OSR = (size_t)(2 * KS) * OSR_SLICE * 4;

  char* ws = (char*)d_ws;
  bf16_t* Wt   = (bf16_t*)(ws);
  bf16_t* Zt   = (bf16_t*)(ws + SZ_WT);
  float*  Osr  = (float*)(ws + SZ_WT + SZ_ZT);
  // scan scratch aliases Osr (dead before k_gemm writes Osr)
  float*  Psub  = Osr;                                     // 2 MB
  float*  Pseg  = (float*)((char*)Psub + 4 * SZ_SEG);
  float*  Ssum  = (float*)((char*)Pseg + SZ_SEG);
  float*  Ssq   = (float*)((char*)Ssum + SZ_SEG);
  float*  Carry = (float*)((char*)Ssq + SZ_SEG);
  char* tail = ws + SZ_WT + SZ_ZT + SZ_OSR;
  float* Mbuf = (float*)tail;                 tail += SZ_M;
  float* cvec = (float*)tail;                 tail += SZ_CV;
  float* S    = (float*)tail;                 tail += SZ_S;
  float* Spart = (float*)tail;                tail += SZ_SP;
  float* mean = (float*)tail;                 tail += (size_t)Bn * Cn * 4;
  float* rstd = (float*)tail;                 tail += (size_t)Bn * Cn * 4;
  float* stdv = (float*)tail;

  k_preA<<<2048, 256, 0, stream>>>(st_w, tt_w, x, alpha, Wt, Spart, Psub, Pseg, Ssum, Ssq);
  k_mid<<<16, 256, 0, stream>>>(x, alpha, rev_w, rev_b, Pseg, Ssum, Ssq,
                                se_w, sp_w, se_b, sp_b, te_w, tp_w, te_b, tp_b, Spart,
                                mean, rstd, stdv, Carry, Mbuf, cvec, S);
  k_scanC<<<dim3(32, 16), dim3(64, 4), 0, stream>>>(x, alpha, rev_w, rev_b, mean, rstd, Carry, Psub, Zt);
  if (KS == 4) {
    k_gemm<4><<<768, 256, 0, stream>>>(Wt, Zt, Osr);
    k_epi<4><<<720, 256, 0, stream>>>(Osr, Mbuf, cvec, S, st_b, tt_b, rev_w, rev_b, mean, stdv, out);
  } else {
    k_gemm<1><<<192, 256, 0, stream>>>(Wt, Zt, Osr);
    k_epi<1><<<720, 256, 0, stream>>>(Osr, Mbuf, cvec, S, st_b, tt_b, rev_w, rev_b, mean, stdv, out);
  }
}

// Round 16
// 108.334 us; speedup vs baseline: 1.0112x; 1.0068x over previous
//
#include <hip/hip_runtime.h>
#include <hip/hip_bf16.h>
#include <hip/hip_fp16.h>
#include <string.h>
#include <stdint.h>

typedef __hip_bfloat16 bf16_t;
typedef float f32x4 __attribute__((ext_vector_type(4)));
typedef short bf16x8 __attribute__((ext_vector_type(8)));

static constexpr int Bn = 32, Ln = 4096, Cn = 64, Hn = 720, HPn = 768;
static constexpr float EPSf = 1e-5f;

static constexpr size_t OSR_SLICE = (size_t)Bn * Hn * Cn;   // elements per K-slice per path

__device__ __forceinline__ short f2bf(float f) {
  bf16_t h = __float2bfloat16(f);
  unsigned short u; memcpy(&u, &h, 2);
  return (short)u;
}

__device__ __forceinline__ float sigm(float v) { return 1.f / (1.f + expf(-v)); }

// ================= kernel 1 (fused): wprep(1536, f32x4 reads) | scanA(512) =================
__global__ void __launch_bounds__(256) k_preA(
    const float* __restrict__ st_w, const float* __restrict__ tt_w,
    const float* __restrict__ x, const float* __restrict__ alpha,
    bf16_t* __restrict__ Wt, float* __restrict__ Spart,
    float* __restrict__ Psub, float* __restrict__ Pseg,
    float* __restrict__ Ssum, float* __restrict__ Ssq) {
  __shared__ __align__(16) char smem[20736];
  int bid = blockIdx.x, t = threadIdx.x;

  if (bid < 1536) {
    // -------- wprep: tw -> fragment-major AF (+Spart colsum partials), f32x4 global reads ------
    float (*tile)[65] = (float(*)[65])smem;             // 16640 B (pad 65: conflict-free emit)
    float (*cs16)[64] = (float(*)[64])(smem + 16640);   // 4096 B
    int p = bid / 768, rem = bid % 768;
    int lc = rem & 63, hc = rem >> 6;
    const float* W = p ? tt_w : st_w;                   // (4096, 720)
    int l0 = lc * 64, h0 = hc * 64;
    int g16 = t >> 4, c4l = (t & 15) * 4;
    int h = h0 + c4l;
    f32x4 ps = (f32x4){0.f, 0.f, 0.f, 0.f};
#pragma unroll
    for (int rr = 0; rr < 4; ++rr) {
      int r = rr * 16 + g16;
      const float* src = &W[(size_t)(l0 + r) * Hn + h];
      f32x4 v;
      if (h + 3 < Hn) {
        v = *reinterpret_cast<const f32x4*>(src);
      } else {
#pragma unroll
        for (int i = 0; i < 4; ++i) v[i] = (h + i < Hn) ? src[i] : 0.f;
      }
      tile[r][c4l + 0] = v[0]; tile[r][c4l + 1] = v[1];
      tile[r][c4l + 2] = v[2]; tile[r][c4l + 3] = v[3];
      ps += v;
    }
    *reinterpret_cast<f32x4*>(&cs16[g16][c4l]) = ps;
    __syncthreads();
    if (t < 64) {
      float s = 0.f;
#pragma unroll
      for (int g = 0; g < 16; ++g) s += cs16[g][t];
      Spart[((size_t)p * 64 + lc) * 768 + h0 + t] = s;
    }
    short* AF = (short*)Wt + (size_t)p * HPn * Ln;
#pragma unroll
    for (int u = 0; u < 2; ++u) {
      int uid = u * 256 + t;
      int ln = uid & 63, ktl = (uid >> 6) & 1, htl = uid >> 7;
      int fr = ln & 15, hi = ln >> 4;
      int ll = ktl * 32 + hi * 8;
      int hh = htl * 16 + fr;
      bf16x8 v;
#pragma unroll
      for (int e = 0; e < 8; ++e) v[e] = f2bf(tile[ll + e][hh]);
      size_t ht = (size_t)(h0 >> 4) + htl, ktg = (size_t)(l0 >> 5) + ktl;
      *reinterpret_cast<bf16x8*>(&AF[((ht * 128 + ktg) << 9) + ((size_t)ln << 3)]) = v;
    }
  } else {
    // ---------------- scanA: (c-quad x l-sub16) raw-x partials + seg reduce ----------------
    float (*lp)[64] = (float(*)[64])smem;
    float (*ls)[64] = (float(*)[64])(smem + 4096);
    float (*lq)[64] = (float(*)[64])(smem + 8192);
    int idx = bid - 1536;
    int b = idx >> 4, sg = idx & 15;
    int ty = t >> 6, tx = t & 63;
    int s = sg * 4 + ty;
    int c4 = (tx & 15) * 4, sub = tx >> 4;
    float a[4], k1[4];
#pragma unroll
    for (int i = 0; i < 4; ++i) { a[i] = sigm(alpha[c4 + i]); k1[i] = 1.f - a[i]; }
    const float* xb = x + ((size_t)b * Ln + s * 64 + sub * 16) * Cn + c4;
    float pr[4] = {0.f, 0.f, 0.f, 0.f}, sm[4] = {0.f, 0.f, 0.f, 0.f}, sq[4] = {0.f, 0.f, 0.f, 0.f};
#pragma unroll
    for (int j = 0; j < 16; ++j) {
      f32x4 v = *reinterpret_cast<const f32x4*>(xb + (size_t)j * Cn);
#pragma unroll
      for (int i = 0; i < 4; ++i) {
        sm[i] += v[i];
        sq[i] = fmaf(v[i], v[i], sq[i]);
        pr[i] = fmaf(a[i], pr[i], k1[i] * v[i]);
      }
    }
    *reinterpret_cast<f32x4*>(&Psub[(((size_t)b * 64 + s) * 4 + sub) * 64 + c4]) =
        (f32x4){pr[0], pr[1], pr[2], pr[3]};
#pragma unroll
    for (int i = 0; i < 4; ++i) {
      lp[ty * 4 + sub][c4 + i] = pr[i];
      ls[ty * 4 + sub][c4 + i] = sm[i];
      lq[ty * 4 + sub][c4 + i] = sq[i];
    }
    __syncthreads();
    int c = tx;
    float av = sigm(alpha[c]);
    float a16 = av * av; a16 *= a16; a16 *= a16; a16 *= a16;   // a^16
    float P = ((lp[ty * 4 + 0][c] * a16 + lp[ty * 4 + 1][c]) * a16 + lp[ty * 4 + 2][c]) * a16 + lp[ty * 4 + 3][c];
    int oidx = (b * 64 + s) * 64 + c;
    Pseg[oidx] = P;
    Ssum[oidx] = ls[ty * 4 + 0][c] + ls[ty * 4 + 1][c] + ls[ty * 4 + 2][c] + ls[ty * 4 + 3][c];
    Ssq[oidx]  = lq[ty * 4 + 0][c] + lq[ty * 4 + 1][c] + lq[ty * 4 + 2][c] + lq[ty * 4 + 3][c];
  }
}

// ====== kernel 2 (fused, 16 blocks): scanB(8) | prep(2) | S-reduce(6) ======
__global__ void __launch_bounds__(256) k_mid(
    const float* __restrict__ x, const float* __restrict__ alpha,
    const float* __restrict__ rev_w, const float* __restrict__ rev_b,
    const float* __restrict__ Pseg, const float* __restrict__ Ssum, const float* __restrict__ Ssq,
    const float* __restrict__ se_w, const float* __restrict__ sp_w,
    const float* __restrict__ se_b, const float* __restrict__ sp_b,
    const float* __restrict__ te_w, const float* __restrict__ tp_w,
    const float* __restrict__ te_b, const float* __restrict__ tp_b,
    const float* __restrict__ Spart,
    float* __restrict__ mean, float* __restrict__ rstd, float* __restrict__ stdv,
    float* __restrict__ CarryIn, float* __restrict__ M, float* __restrict__ cvec,
    float* __restrict__ S) {
  __shared__ __align__(16) char smem[35072];
  int bid = blockIdx.x, t = threadIdx.x;

  if (bid < 8) {
    // ---------------- scanB: stats finalize + 64-step carry scan ----------------
    int b = bid * 4 + (t >> 6), c = t & 63;
    float sm = 0.f, sq = 0.f;
#pragma unroll 8
    for (int s = 0; s < 64; ++s) {
      int idx = (b * 64 + s) * 64 + c;
      sm += Ssum[idx]; sq += Ssq[idx];
    }
    float mn = sm * (1.f / 4096.f);
    float var = sq * (1.f / 4096.f) - mn * mn;
    float sd = sqrtf(var + EPSf);
    float rs = 1.f / sd;
    mean[b * 64 + c] = mn; stdv[b * 64 + c] = sd; rstd[b * 64 + c] = rs;

    float w = rev_w[c], rb = rev_b[c];
    float g = rs * w, d = rb - mn * g;         // xn = g*x + d
    float a = sigm(alpha[c]);
    float a2 = a * a, a4 = a2 * a2, a8 = a4 * a4, a16 = a8 * a8, a32 = a16 * a16;
    float a64 = a32 * a32;
    float dk1s = d * (1.f - a64);
    float carry = fmaf(g, x[((size_t)b * Ln) * Cn + c], d);   // xn[0]
    for (int so = 0; so < 8; ++so) {
      float pv[8];
#pragma unroll
      for (int i = 0; i < 8; ++i)
        pv[i] = Pseg[((size_t)(b * 64 + so * 8 + i)) * 64 + c];
#pragma unroll
      for (int i = 0; i < 8; ++i) {
        CarryIn[((size_t)(b * 64 + so * 8 + i)) * 64 + c] = carry;
        carry = fmaf(a64, carry, fmaf(g, pv[i], dk1s));
      }
    }
  } else if (bid < 10) {
    // ---------------- prep: fold the two 64->512->64 MLPs ----------------
    float (*ews)[68] = (float(*)[68])smem;
    float (*pws)[68] = (float(*)[68])(smem + 17408);
    float* ebs = (float*)(smem + 34816);
    int p = bid - 8;
    const float* ew = p ? te_w : se_w;   // (64,512)
    const float* pw = p ? tp_w : sp_w;   // (512,64)
    const float* eb = p ? te_b : se_b;   // (512,)
    const float* pb = p ? tp_b : sp_b;   // (64,)
    int r0 = (t >> 4) * 4, c0 = (t & 15) * 4;
    float acc[4][4];
#pragma unroll
    for (int i = 0; i < 4; ++i)
#pragma unroll
      for (int j = 0; j < 4; ++j) acc[i][j] = 0.f;
    float cv = 0.f;
    for (int dc = 0; dc < 8; ++dc) {
      int d0 = dc * 64;
#pragma unroll
      for (int q = 0; q < 4; ++q) {
        int fi = t * 4 + q;
        int r = fi >> 4, dd = (fi * 4) & 63;
        *reinterpret_cast<f32x4*>(&ews[r][dd]) = *reinterpret_cast<const f32x4*>(&ew[r * 512 + d0 + dd]);
        *reinterpret_cast<f32x4*>(&pws[r][dd]) = *reinterpret_cast<const f32x4*>(&pw[(d0 + r) * 64 + dd]);
      }
      if (t < 64) ebs[t] = eb[d0 + t];
      __syncthreads();
#pragma unroll 4
      for (int g = 0; g < 16; ++g) {
        int dd = g * 4;
        f32x4 av[4], bv[4];
#pragma unroll
        for (int i = 0; i < 4; ++i) av[i] = *reinterpret_cast<const f32x4*>(&ews[r0 + i][dd]);
#pragma unroll
        for (int d = 0; d < 4; ++d) bv[d] = *reinterpret_cast<const f32x4*>(&pws[dd + d][c0]);
#pragma unroll
        for (int d = 0; d < 4; ++d)
#pragma unroll
          for (int i = 0; i < 4; ++i)
#pragma unroll
            for (int j = 0; j < 4; ++j) acc[i][j] = fmaf(av[i][d], bv[d][j], acc[i][j]);
      }
      if (t < 64) {
#pragma unroll 8
        for (int dd = 0; dd < 64; ++dd) cv = fmaf(ebs[dd], pws[dd][t], cv);
      }
      __syncthreads();
    }
#pragma unroll
    for (int i = 0; i < 4; ++i)
#pragma unroll
      for (int j = 0; j < 4; ++j)
        M[p * 4096 + (r0 + i) * 64 + c0 + j] = acc[i][j];
    if (t < 64) cvec[p * 64 + t] = cv + pb[t];
  } else {
    // ---------------- S-reduce: S[p][h] = sum_lc Spart[p][lc][h] ----------------
    int idx = (bid - 10) * 256 + t;              // 0..1535
    int p = idx / 768, h = idx % 768;
    float s = 0.f;
#pragma unroll 8
    for (int lc = 0; lc < 64; ++lc)
      s += Spart[((size_t)p * 64 + lc) * 768 + h];
    S[p * 768 + h] = s;
  }
}

// ---------------- kernel 3c: apply scan, write FRAGMENT-MAJOR bf16 via wave-local LDS stage ----
__global__ void __launch_bounds__(256) k_scanC(const float* __restrict__ x, const float* __restrict__ alpha,
                                               const float* __restrict__ rev_w, const float* __restrict__ rev_b,
                                               const float* __restrict__ mean, const float* __restrict__ rstd,
                                               const float* __restrict__ CarryIn, const float* __restrict__ Psub,
                                               bf16_t* __restrict__ Zt) {
  int b = blockIdx.x, ty = threadIdx.y, s = blockIdx.y * 4 + ty, t = threadIdx.x;
  int c4 = (t & 15) * 4, sub = t >> 4;
  float g[4], d[4], a[4], k1[4], a16[4], dk[4], tr[4];
#pragma unroll
  for (int i = 0; i < 4; ++i) {
    int c = c4 + i;
    float rs = rstd[b * 64 + c];
    g[i] = rs * rev_w[c]; d[i] = rev_b[c] - mean[b * 64 + c] * g[i];
    a[i] = sigm(alpha[c]); k1[i] = 1.f - a[i];
    float v = a[i] * a[i]; v *= v; v *= v; v *= v;
    a16[i] = v;
    dk[i] = d[i] * (1.f - v);
  }
  f32x4 cs = *reinterpret_cast<const f32x4*>(&CarryIn[((size_t)b * 64 + s) * 64 + c4]);
#pragma unroll
  for (int i = 0; i < 4; ++i) tr[i] = cs[i];
  for (int k = 0; k < sub; ++k) {            // compose prior subs (<=3 iters, masked)
    f32x4 p = *reinterpret_cast<const f32x4*>(&Psub[(((size_t)b * 64 + s) * 4 + k) * 64 + c4]);
#pragma unroll
    for (int i = 0; i < 4; ++i) tr[i] = fmaf(a16[i], tr[i], fmaf(g[i], p[i], dk[i]));
  }
  const float* xb = x + ((size_t)b * Ln + s * 64 + sub * 16) * Cn + c4;
  bf16x8 vs[4][2], vt[4][2];
#pragma unroll
  for (int j = 0; j < 16; ++j) {
    f32x4 v = *reinterpret_cast<const f32x4*>(xb + (size_t)j * Cn);
#pragma unroll
    for (int i = 0; i < 4; ++i) {
      float xn = fmaf(g[i], v[i], d[i]);
      tr[i] = fmaf(a[i], tr[i], k1[i] * xn);
      vs[i][j >> 3][j & 7] = f2bf(xn - tr[i]);
      vt[i][j >> 3][j & 7] = f2bf(tr[i]);
    }
  }
  // ---- fragment-major emit via LDS staging (per-wave, no cross-wave sharing) ----
  __shared__ short stage[4][8][520];         // 4 waves x 8 units x (512 + 8 pad) shorts = 33.3 KB
  short* BF0 = (short*)Zt;                   // path 0: seasonal
  const size_t PATH = (size_t)Bn * Cn * Ln;  // shorts per path
  int cq = (t & 15) >> 2;                    // unit n-part within wave
  int u = cq * 2 + (sub >> 1);               // unit index 0..7
  int hb = (sub & 1) * 2;                    // hi base {0, 2}
  // pass 1: seasonal
#pragma unroll
  for (int i = 0; i < 4; ++i) {
    int frv = (c4 & 15) + i;
    *reinterpret_cast<bf16x8*>(&stage[ty][u][(hb * 16 + frv) * 8]) = vs[i][0];
    *reinterpret_cast<bf16x8*>(&stage[ty][u][((hb + 1) * 16 + frv) * 8]) = vs[i][1];
  }
#pragma unroll
  for (int uu = 0; uu < 8; ++uu) {
    size_t nt = (size_t)b * 4 + (uu >> 1), ktg = (size_t)s * 2 + (uu & 1);
    *reinterpret_cast<bf16x8*>(BF0 + ((nt * 128 + ktg) << 9) + ((size_t)t << 3)) =
        *reinterpret_cast<const bf16x8*>(&stage[ty][uu][t * 8]);
  }
  // pass 2: trend (reuse buffer; wave-local ordering via lgkmcnt, no barrier needed)
#pragma unroll
  for (int i = 0; i < 4; ++i) {
    int frv = (c4 & 15) + i;
    *reinterpret_cast<bf16x8*>(&stage[ty][u][(hb * 16 + frv) * 8]) = vt[i][0];
    *reinterpret_cast<bf16x8*>(&stage[ty][u][((hb + 1) * 16 + frv) * 8]) = vt[i][1];
  }
#pragma unroll
  for (int uu = 0; uu < 8; ++uu) {
    size_t nt = (size_t)b * 4 + (uu >> 1), ktg = (size_t)s * 2 + (uu & 1);
    *reinterpret_cast<bf16x8*>(BF0 + PATH + ((nt * 128 + ktg) << 9) + ((size_t)t << 3)) =
        *reinterpret_cast<const bf16x8*>(&stage[ty][uu][t * 8]);
  }
}

// ---------------- kernel 5: bf16 MFMA GEMM — LDS-FREE, depth-2 register pipeline ----------------
// Both operands fragment-major in global. 3 named buffer sets (rule #20): 16 loads/wave in
// flight, covering ~2 steps of L2 latency. fp16 Osr output (halves HBM writes).
template <int KS>
__global__ void __launch_bounds__(256, 2) k_gemm(const bf16_t* __restrict__ Wt, const bf16_t* __restrict__ Zt,
                                                 __half* __restrict__ Osr) {
  // XCD-chunked bijective swizzle (gridDim.x % 8 == 0)
  int per = gridDim.x >> 3;
  int swz = (blockIdx.x & 7) * per + (blockIdx.x >> 3);
  int z = swz / 96, rem = swz % 96;                   // 96 = 16 x-blocks * 6 y-blocks
  int by = rem >> 4, bx = rem & 15;
  int p = z / KS, kq = z % KS;
  const short* AF = (const short*)Wt + (size_t)p * HPn * Ln;
  const short* BF = (const short*)Zt + (size_t)p * (Bn * Cn) * Ln;
  int h0 = by * 128, n0 = bx * 128;
  int kbase = kq * (Ln / KS);
  const int NT = (Ln / KS) / 32;                      // K-steps of 32
  int tid = threadIdx.x, wid = tid >> 6, lane = tid & 63;
  int wr = wid >> 1, wc = wid & 1;
  int fr = lane & 15, hi = lane >> 4;
  const short* ab = AF + ((((size_t)(h0 >> 4) + wr * 4) * 128 + (kbase >> 5)) << 9) + ((size_t)lane << 3);
  const short* bb = BF + ((((size_t)(n0 >> 4) + wc * 4) * 128 + (kbase >> 5)) << 9) + ((size_t)lane << 3);

  f32x4 acc[4][4];
#pragma unroll
  for (int i = 0; i < 4; ++i)
#pragma unroll
    for (int j = 0; j < 4; ++j) acc[i][j] = (f32x4){0.f, 0.f, 0.f, 0.f};

  auto LOAD = [&](bf16x8 (&a)[4], bf16x8 (&b)[4], int kt) {
#pragma unroll
    for (int i = 0; i < 4; ++i)
      a[i] = *reinterpret_cast<const bf16x8*>(ab + (((size_t)i * 128 + kt) << 9));
#pragma unroll
    for (int j = 0; j < 4; ++j)
      b[j] = *reinterpret_cast<const bf16x8*>(bb + (((size_t)j * 128 + kt) << 9));
  };
  auto COMPUTE = [&](const bf16x8 (&a)[4], const bf16x8 (&b)[4]) {
    __builtin_amdgcn_s_setprio(1);
#pragma unroll
    for (int i = 0; i < 4; ++i)
#pragma unroll
      for (int j = 0; j < 4; ++j)
        acc[i][j] = __builtin_amdgcn_mfma_f32_16x16x32_bf16(a[i], b[j], acc[i][j], 0, 0, 0);
    __builtin_amdgcn_s_setprio(0);
  };

  bf16x8 a0[4], b0[4], a1[4], b1[4], a2[4], b2[4];    // 3 named buffer sets (rule #20)
  LOAD(a0, b0, 0);
  if (NT > 1) LOAD(a1, b1, 1);
  for (int t = 0; t < NT; t += 3) {
    if (t + 2 < NT) LOAD(a2, b2, t + 2);
    COMPUTE(a0, b0);
    if (t + 3 < NT) LOAD(a0, b0, t + 3);
    if (t + 1 < NT) COMPUTE(a1, b1);
    if (t + 4 < NT) LOAD(a1, b1, t + 4);
    if (t + 2 < NT) COMPUTE(a2, b2);
  }

#pragma unroll
  for (int i = 0; i < 4; ++i) {
#pragma unroll
    for (int j = 0; j < 4; ++j) {
#pragma unroll
      for (int r = 0; r < 4; ++r) {
        int m = wr * 64 + i * 16 + hi * 4 + r;
        int h = h0 + m;
        if (h < Hn) {
          int n = n0 + wc * 64 + j * 16 + fr;
          int bidx = n >> 6, c = n & 63;
          Osr[(((size_t)z * Bn + bidx) * Hn + h) * Cn + c] = __float2half(acc[i][j][r]);
        }
      }
    }
  }
}

// ---------------- kernel 6: epilogue — 32 rows/block, fp16 Osr reads ----------
template <int KS>
__global__ void __launch_bounds__(256) k_epi(const __half* __restrict__ Osr, const float* __restrict__ M,
                                             const float* __restrict__ cvec, const float* __restrict__ S,
                                             const float* __restrict__ st_b, const float* __restrict__ tt_b,
                                             const float* __restrict__ rev_w, const float* __restrict__ rev_b,
                                             const float* __restrict__ mean, const float* __restrict__ stdv,
                                             float* __restrict__ out) {
  __shared__ float Msh[2][64][64];    // 32 KB
  __shared__ float rowS[32][64];      // 8 KB
  __shared__ float rowT[32][64];      // 8 KB
  int t = threadIdx.x;
  for (int i = t; i < 2048; i += 256)   // vectorized Msh stage (8 x b128 per thread)
    reinterpret_cast<f32x4*>(Msh)[i] = reinterpret_cast<const f32x4*>(M)[i];
  int c = t & 63, grp = t >> 6;       // grp 0..3, 8 rows each
  float w = rev_w[c], rb = rev_b[c];
  float cs = cvec[c], ct = cvec[64 + c];
  int base = blockIdx.x * 32;
#pragma unroll
  for (int k = 0; k < 8; ++k) {
    int rl = grp * 8 + k;
    int r = base + rl;
    int b = r / 720, h = r % 720;
    float vs = 0.f, vt = 0.f;
#pragma unroll
    for (int kq = 0; kq < KS; ++kq) {
      vs += __half2float(Osr[(((size_t)kq * Bn + b) * Hn + h) * Cn + c]);
      vt += __half2float(Osr[(((size_t)(KS + kq) * Bn + b) * Hn + h) * Cn + c]);
    }
    rowS[rl][c] = vs;
    rowT[rl][c] = vt;
  }
  __syncthreads();
  float acc[8];
  int hh[8], bb[8];
#pragma unroll
  for (int k = 0; k < 8; ++k) {
    int r = base + grp * 8 + k;
    bb[k] = r / 720; hh[k] = r % 720;
    acc[k] = cs * S[hh[k]] + ct * S[768 + hh[k]] + st_b[hh[k]] + tt_b[hh[k]];
  }
  int r0 = grp * 8;
  for (int cq = 0; cq < 16; ++cq) {
    f32x4 rs[8], rt[8];
#pragma unroll
    for (int k = 0; k < 8; ++k) rs[k] = *reinterpret_cast<const f32x4*>(&rowS[r0 + k][cq * 4]);
#pragma unroll
    for (int k = 0; k < 8; ++k) rt[k] = *reinterpret_cast<const f32x4*>(&rowT[r0 + k][cq * 4]);
#pragma unroll
    for (int i = 0; i < 4; ++i) {
      float m0 = Msh[0][cq * 4 + i][c], m1 = Msh[1][cq * 4 + i][c];
#pragma unroll
      for (int k = 0; k < 8; ++k)
        acc[k] = fmaf(rs[k][i], m0, fmaf(rt[k][i], m1, acc[k]));
    }
  }
  float winv = 1.f / (w + EPSf);
#pragma unroll
  for (int k = 0; k < 8; ++k) {
    float o = (acc[k] - rb) * winv * stdv[bb[k] * Cn + c] + mean[bb[k] * Cn + c];
    out[(size_t)(base + r0 + k) * 64 + c] = o;
  }
}

// ---------------- launch ----------------
extern "C" void kernel_launch(void* const* d_in, const int* in_sizes, int n_in,
                              void* d_out, int out_size, void* d_ws, size_t ws_size,
                              hipStream_t stream) {
  const float* x     = (const float*)d_in[0];
  const float* alpha = (const float*)d_in[1];
  const float* rev_w = (const float*)d_in[2];
  const float* rev_b = (const float*)d_in[3];
  const float* se_w  = (const float*)d_in[4];
  const float* se_b  = (const float*)d_in[5];
  const float* sp_w  = (const float*)d_in[6];
  const float* sp_b  = (const float*)d_in[7];
  const float* st_w  = (const float*)d_in[8];
  const float* st_b  = (const float*)d_in[9];
  const float* te_w  = (const float*)d_in[10];
  const float* te_b  = (const float*)d_in[11];
  const float* tp_w  = (const float*)d_in[12];
  const float* tp_b  = (const float*)d_in[13];
  const float* tt_w  = (const float*)d_in[14];
  const float* tt_b  = (const float*)d_in[15];
  float* out = (float*)d_out;

  const size_t SZ_WT  = (size_t)2 * HPn * Ln * 2;          // 12.58 MB (fragment-major AF)
  const size_t SZ_ZT  = (size_t)2 * Bn * Cn * Ln * 2;      // 33.55 MB (fragment-major BF)
  const size_t SZ_SEG = (size_t)Bn * 64 * 64 * 4;          // 0.5 MB seg-level scratch
  const size_t SZ_M   = 2 * 64 * 64 * 4;                   // 32 KB
  const size_t SZ_CV  = 2 * 64 * 4;
  const size_t SZ_S   = 2 * 768 * 4;
  const size_t SZ_SP  = (size_t)2 * 64 * 768 * 4;          // Spart 393 KB
  const size_t TAIL   = SZ_M + SZ_CV + SZ_S + SZ_SP + 3 * (size_t)Bn * Cn * 4;

  // fp16 Osr: KS=4 needs 8 slices x 2B; scan scratch (6 MB) still fits in the Osr region.
  const size_t NEED4 = SZ_WT + SZ_ZT + 8 * OSR_SLICE * 2 + TAIL;
  const int KS = (ws_size >= NEED4) ? 4 : 1;
  size_t SZ_OSR = (size_t)(2 * KS) * OSR_SLICE * 2;
  const size_t SZ_SCRATCH = 4 * SZ_SEG + 4 * SZ_SEG;       // Psub(4) + Pseg/Ssum/Ssq/Carry(4)
  if (SZ_OSR < SZ_SCRATCH) SZ_OSR = SZ_SCRATCH;            // region shared with scan scratch

  char* ws = (char*)d_ws;
  bf16_t* Wt   = (bf16_t*)(ws);
  bf16_t* Zt   = (bf16_t*)(ws + SZ_WT);
  __half* Osr  = (__half*)(ws + SZ_WT + SZ_ZT);
  // scan scratch aliases Osr (dead before k_gemm writes Osr)
  float*  Psub  = (float*)Osr;                             // 2 MB
  float*  Pseg  = (float*)((char*)Psub + 4 * SZ_SEG);
  float*  Ssum  = (float*)((char*)Pseg + SZ_SEG);
  float*  Ssq   = (float*)((char*)Ssum + SZ_SEG);
  float*  Carry = (float*)((char*)Ssq + SZ_SEG);
  char* tail = ws + SZ_WT + SZ_ZT + SZ_OSR;
  float* Mbuf = (float*)tail;                 tail += SZ_M;
  float* cvec = (float*)tail;                 tail += SZ_CV;
  float* S    = (float*)tail;                 tail += SZ_S;
  float* Spart = (float*)tail;                tail += SZ_SP;
  float* mean = (float*)tail;                 tail += (size_t)Bn * Cn * 4;
  float* rstd = (float*)tail;                 tail += (size_t)Bn * Cn * 4;
  float* stdv = (float*)tail;

  k_preA<<<2048, 256, 0, stream>>>(st_w, tt_w, x, alpha, Wt, Spart, Psub, Pseg, Ssum, Ssq);
  k_mid<<<16, 256, 0, stream>>>(x, alpha, rev_w, rev_b, Pseg, Ssum, Ssq,
                                se_w, sp_w, se_b, sp_b, te_w, tp_w, te_b, tp_b, Spart,
                                mean, rstd, stdv, Carry, Mbuf, cvec, S);
  k_scanC<<<dim3(32, 16), dim3(64, 4), 0, stream>>>(x, alpha, rev_w, rev_b, mean, rstd, Carry, Psub, Zt);
  if (KS == 4) {
    k_gemm<4><<<768, 256, 0, stream>>>(Wt, Zt, Osr);
    k_epi<4><<<720, 256, 0, stream>>>(Osr, Mbuf, cvec, S, st_b, tt_b, rev_w, rev_b, mean, stdv, out);
  } else {
    k_gemm<1><<<192, 256, 0, stream>>>(Wt, Zt, Osr);
    k_epi<1><<<720, 256, 0, stream>>>(Osr, Mbuf, cvec, S, st_b, tt_b, rev_w, rev_b, mean, stdv, out);
  }
}

// Round 17
// 105.483 us; speedup vs baseline: 1.0385x; 1.0270x over previous
//
#include <hip/hip_runtime.h>
#include <hip/hip_bf16.h>
#include <hip/hip_fp16.h>
#include <string.h>
#include <stdint.h>

typedef __hip_bfloat16 bf16_t;
typedef float f32x4 __attribute__((ext_vector_type(4)));
typedef short bf16x8 __attribute__((ext_vector_type(8)));

static constexpr int Bn = 32, Ln = 4096, Cn = 64, Hn = 720, HPn = 768;
static constexpr float EPSf = 1e-5f;

static constexpr size_t OSR_SLICE = (size_t)Bn * Hn * Cn;   // elements per K-slice per path

__device__ __forceinline__ short f2bf(float f) {
  bf16_t h = __float2bfloat16(f);
  unsigned short u; memcpy(&u, &h, 2);
  return (short)u;
}

__device__ __forceinline__ float sigm(float v) { return 1.f / (1.f + expf(-v)); }

// ================= kernel 1 (fused): wprep(1536, f32x4 reads) | scanA(512) =================
__global__ void __launch_bounds__(256) k_preA(
    const float* __restrict__ st_w, const float* __restrict__ tt_w,
    const float* __restrict__ x, const float* __restrict__ alpha,
    bf16_t* __restrict__ Wt, float* __restrict__ Spart,
    float* __restrict__ Psub, float* __restrict__ Pseg,
    float* __restrict__ Ssum, float* __restrict__ Ssq) {
  __shared__ __align__(16) char smem[20736];
  int bid = blockIdx.x, t = threadIdx.x;

  if (bid < 1536) {
    // -------- wprep: tw -> fragment-major AF (+Spart colsum partials), f32x4 global reads ------
    float (*tile)[65] = (float(*)[65])smem;             // 16640 B (pad 65: conflict-free emit)
    float (*cs16)[64] = (float(*)[64])(smem + 16640);   // 4096 B
    int p = bid / 768, rem = bid % 768;
    int lc = rem & 63, hc = rem >> 6;
    const float* W = p ? tt_w : st_w;                   // (4096, 720)
    int l0 = lc * 64, h0 = hc * 64;
    int g16 = t >> 4, c4l = (t & 15) * 4;
    int h = h0 + c4l;
    f32x4 ps = (f32x4){0.f, 0.f, 0.f, 0.f};
#pragma unroll
    for (int rr = 0; rr < 4; ++rr) {
      int r = rr * 16 + g16;
      const float* src = &W[(size_t)(l0 + r) * Hn + h];
      f32x4 v;
      if (h + 3 < Hn) {
        v = *reinterpret_cast<const f32x4*>(src);
      } else {
#pragma unroll
        for (int i = 0; i < 4; ++i) v[i] = (h + i < Hn) ? src[i] : 0.f;
      }
      tile[r][c4l + 0] = v[0]; tile[r][c4l + 1] = v[1];
      tile[r][c4l + 2] = v[2]; tile[r][c4l + 3] = v[3];
      ps += v;
    }
    *reinterpret_cast<f32x4*>(&cs16[g16][c4l]) = ps;
    __syncthreads();
    if (t < 64) {
      float s = 0.f;
#pragma unroll
      for (int g = 0; g < 16; ++g) s += cs16[g][t];
      Spart[((size_t)p * 64 + lc) * 768 + h0 + t] = s;
    }
    short* AF = (short*)Wt + (size_t)p * HPn * Ln;
#pragma unroll
    for (int u = 0; u < 2; ++u) {
      int uid = u * 256 + t;
      int ln = uid & 63, ktl = (uid >> 6) & 1, htl = uid >> 7;
      int fr = ln & 15, hi = ln >> 4;
      int ll = ktl * 32 + hi * 8;
      int hh = htl * 16 + fr;
      bf16x8 v;
#pragma unroll
      for (int e = 0; e < 8; ++e) v[e] = f2bf(tile[ll + e][hh]);
      size_t ht = (size_t)(h0 >> 4) + htl, ktg = (size_t)(l0 >> 5) + ktl;
      *reinterpret_cast<bf16x8*>(&AF[((ht * 128 + ktg) << 9) + ((size_t)ln << 3)]) = v;
    }
  } else {
    // ---------------- scanA: (c-quad x l-sub16) raw-x partials + seg reduce ----------------
    float (*lp)[64] = (float(*)[64])smem;
    float (*ls)[64] = (float(*)[64])(smem + 4096);
    float (*lq)[64] = (float(*)[64])(smem + 8192);
    int idx = bid - 1536;
    int b = idx >> 4, sg = idx & 15;
    int ty = t >> 6, tx = t & 63;
    int s = sg * 4 + ty;
    int c4 = (tx & 15) * 4, sub = tx >> 4;
    float a[4], k1[4];
#pragma unroll
    for (int i = 0; i < 4; ++i) { a[i] = sigm(alpha[c4 + i]); k1[i] = 1.f - a[i]; }
    const float* xb = x + ((size_t)b * Ln + s * 64 + sub * 16) * Cn + c4;
    float pr[4] = {0.f, 0.f, 0.f, 0.f}, sm[4] = {0.f, 0.f, 0.f, 0.f}, sq[4] = {0.f, 0.f, 0.f, 0.f};
#pragma unroll
    for (int j = 0; j < 16; ++j) {
      f32x4 v = *reinterpret_cast<const f32x4*>(xb + (size_t)j * Cn);
#pragma unroll
      for (int i = 0; i < 4; ++i) {
        sm[i] += v[i];
        sq[i] = fmaf(v[i], v[i], sq[i]);
        pr[i] = fmaf(a[i], pr[i], k1[i] * v[i]);
      }
    }
    *reinterpret_cast<f32x4*>(&Psub[(((size_t)b * 64 + s) * 4 + sub) * 64 + c4]) =
        (f32x4){pr[0], pr[1], pr[2], pr[3]};
#pragma unroll
    for (int i = 0; i < 4; ++i) {
      lp[ty * 4 + sub][c4 + i] = pr[i];
      ls[ty * 4 + sub][c4 + i] = sm[i];
      lq[ty * 4 + sub][c4 + i] = sq[i];
    }
    __syncthreads();
    int c = tx;
    float av = sigm(alpha[c]);
    float a16 = av * av; a16 *= a16; a16 *= a16; a16 *= a16;   // a^16
    float P = ((lp[ty * 4 + 0][c] * a16 + lp[ty * 4 + 1][c]) * a16 + lp[ty * 4 + 2][c]) * a16 + lp[ty * 4 + 3][c];
    int oidx = (b * 64 + s) * 64 + c;
    Pseg[oidx] = P;
    Ssum[oidx] = ls[ty * 4 + 0][c] + ls[ty * 4 + 1][c] + ls[ty * 4 + 2][c] + ls[ty * 4 + 3][c];
    Ssq[oidx]  = lq[ty * 4 + 0][c] + lq[ty * 4 + 1][c] + lq[ty * 4 + 2][c] + lq[ty * 4 + 3][c];
  }
}

// ====== kernel 2 (fused, 16 blocks): scanB(8) | prep(2) | S-reduce(6) ======
__global__ void __launch_bounds__(256) k_mid(
    const float* __restrict__ x, const float* __restrict__ alpha,
    const float* __restrict__ rev_w, const float* __restrict__ rev_b,
    const float* __restrict__ Pseg, const float* __restrict__ Ssum, const float* __restrict__ Ssq,
    const float* __restrict__ se_w, const float* __restrict__ sp_w,
    const float* __restrict__ se_b, const float* __restrict__ sp_b,
    const float* __restrict__ te_w, const float* __restrict__ tp_w,
    const float* __restrict__ te_b, const float* __restrict__ tp_b,
    const float* __restrict__ Spart,
    float* __restrict__ mean, float* __restrict__ rstd, float* __restrict__ stdv,
    float* __restrict__ CarryIn, float* __restrict__ M, float* __restrict__ cvec,
    float* __restrict__ S) {
  __shared__ __align__(16) char smem[35072];
  int bid = blockIdx.x, t = threadIdx.x;

  if (bid < 8) {
    // ---------------- scanB: stats finalize + 64-step carry scan ----------------
    int b = bid * 4 + (t >> 6), c = t & 63;
    float sm = 0.f, sq = 0.f;
#pragma unroll 8
    for (int s = 0; s < 64; ++s) {
      int idx = (b * 64 + s) * 64 + c;
      sm += Ssum[idx]; sq += Ssq[idx];
    }
    float mn = sm * (1.f / 4096.f);
    float var = sq * (1.f / 4096.f) - mn * mn;
    float sd = sqrtf(var + EPSf);
    float rs = 1.f / sd;
    mean[b * 64 + c] = mn; stdv[b * 64 + c] = sd; rstd[b * 64 + c] = rs;

    float w = rev_w[c], rb = rev_b[c];
    float g = rs * w, d = rb - mn * g;         // xn = g*x + d
    float a = sigm(alpha[c]);
    float a2 = a * a, a4 = a2 * a2, a8 = a4 * a4, a16 = a8 * a8, a32 = a16 * a16;
    float a64 = a32 * a32;
    float dk1s = d * (1.f - a64);
    float carry = fmaf(g, x[((size_t)b * Ln) * Cn + c], d);   // xn[0]
    for (int so = 0; so < 8; ++so) {
      float pv[8];
#pragma unroll
      for (int i = 0; i < 8; ++i)
        pv[i] = Pseg[((size_t)(b * 64 + so * 8 + i)) * 64 + c];
#pragma unroll
      for (int i = 0; i < 8; ++i) {
        CarryIn[((size_t)(b * 64 + so * 8 + i)) * 64 + c] = carry;
        carry = fmaf(a64, carry, fmaf(g, pv[i], dk1s));
      }
    }
  } else if (bid < 10) {
    // ---------------- prep: fold the two 64->512->64 MLPs ----------------
    float (*ews)[68] = (float(*)[68])smem;
    float (*pws)[68] = (float(*)[68])(smem + 17408);
    float* ebs = (float*)(smem + 34816);
    int p = bid - 8;
    const float* ew = p ? te_w : se_w;   // (64,512)
    const float* pw = p ? tp_w : sp_w;   // (512,64)
    const float* eb = p ? te_b : se_b;   // (512,)
    const float* pb = p ? tp_b : sp_b;   // (64,)
    int r0 = (t >> 4) * 4, c0 = (t & 15) * 4;
    float acc[4][4];
#pragma unroll
    for (int i = 0; i < 4; ++i)
#pragma unroll
      for (int j = 0; j < 4; ++j) acc[i][j] = 0.f;
    float cv = 0.f;
    for (int dc = 0; dc < 8; ++dc) {
      int d0 = dc * 64;
#pragma unroll
      for (int q = 0; q < 4; ++q) {
        int fi = t * 4 + q;
        int r = fi >> 4, dd = (fi * 4) & 63;
        *reinterpret_cast<f32x4*>(&ews[r][dd]) = *reinterpret_cast<const f32x4*>(&ew[r * 512 + d0 + dd]);
        *reinterpret_cast<f32x4*>(&pws[r][dd]) = *reinterpret_cast<const f32x4*>(&pw[(d0 + r) * 64 + dd]);
      }
      if (t < 64) ebs[t] = eb[d0 + t];
      __syncthreads();
#pragma unroll 4
      for (int g = 0; g < 16; ++g) {
        int dd = g * 4;
        f32x4 av[4], bv[4];
#pragma unroll
        for (int i = 0; i < 4; ++i) av[i] = *reinterpret_cast<const f32x4*>(&ews[r0 + i][dd]);
#pragma unroll
        for (int d = 0; d < 4; ++d) bv[d] = *reinterpret_cast<const f32x4*>(&pws[dd + d][c0]);
#pragma unroll
        for (int d = 0; d < 4; ++d)
#pragma unroll
          for (int i = 0; i < 4; ++i)
#pragma unroll
            for (int j = 0; j < 4; ++j) acc[i][j] = fmaf(av[i][d], bv[d][j], acc[i][j]);
      }
      if (t < 64) {
#pragma unroll 8
        for (int dd = 0; dd < 64; ++dd) cv = fmaf(ebs[dd], pws[dd][t], cv);
      }
      __syncthreads();
    }
#pragma unroll
    for (int i = 0; i < 4; ++i)
#pragma unroll
      for (int j = 0; j < 4; ++j)
        M[p * 4096 + (r0 + i) * 64 + c0 + j] = acc[i][j];
    if (t < 64) cvec[p * 64 + t] = cv + pb[t];
  } else {
    // ---------------- S-reduce: S[p][h] = sum_lc Spart[p][lc][h] ----------------
    int idx = (bid - 10) * 256 + t;              // 0..1535
    int p = idx / 768, h = idx % 768;
    float s = 0.f;
#pragma unroll 8
    for (int lc = 0; lc < 64; ++lc)
      s += Spart[((size_t)p * 64 + lc) * 768 + h];
    S[p * 768 + h] = s;
  }
}

// ---------------- kernel 3c: apply scan, write FRAGMENT-MAJOR bf16 via wave-local LDS stage ----
__global__ void __launch_bounds__(256) k_scanC(const float* __restrict__ x, const float* __restrict__ alpha,
                                               const float* __restrict__ rev_w, const float* __restrict__ rev_b,
                                               const float* __restrict__ mean, const float* __restrict__ rstd,
                                               const float* __restrict__ CarryIn, const float* __restrict__ Psub,
                                               bf16_t* __restrict__ Zt) {
  int b = blockIdx.x, ty = threadIdx.y, s = blockIdx.y * 4 + ty, t = threadIdx.x;
  int c4 = (t & 15) * 4, sub = t >> 4;
  float g[4], d[4], a[4], k1[4], a16[4], dk[4], tr[4];
#pragma unroll
  for (int i = 0; i < 4; ++i) {
    int c = c4 + i;
    float rs = rstd[b * 64 + c];
    g[i] = rs * rev_w[c]; d[i] = rev_b[c] - mean[b * 64 + c] * g[i];
    a[i] = sigm(alpha[c]); k1[i] = 1.f - a[i];
    float v = a[i] * a[i]; v *= v; v *= v; v *= v;
    a16[i] = v;
    dk[i] = d[i] * (1.f - v);
  }
  f32x4 cs = *reinterpret_cast<const f32x4*>(&CarryIn[((size_t)b * 64 + s) * 64 + c4]);
#pragma unroll
  for (int i = 0; i < 4; ++i) tr[i] = cs[i];
  for (int k = 0; k < sub; ++k) {            // compose prior subs (<=3 iters, masked)
    f32x4 p = *reinterpret_cast<const f32x4*>(&Psub[(((size_t)b * 64 + s) * 4 + k) * 64 + c4]);
#pragma unroll
    for (int i = 0; i < 4; ++i) tr[i] = fmaf(a16[i], tr[i], fmaf(g[i], p[i], dk[i]));
  }
  const float* xb = x + ((size_t)b * Ln + s * 64 + sub * 16) * Cn + c4;
  bf16x8 vs[4][2], vt[4][2];
#pragma unroll
  for (int j = 0; j < 16; ++j) {
    f32x4 v = *reinterpret_cast<const f32x4*>(xb + (size_t)j * Cn);
#pragma unroll
    for (int i = 0; i < 4; ++i) {
      float xn = fmaf(g[i], v[i], d[i]);
      tr[i] = fmaf(a[i], tr[i], k1[i] * xn);
      vs[i][j >> 3][j & 7] = f2bf(xn - tr[i]);
      vt[i][j >> 3][j & 7] = f2bf(tr[i]);
    }
  }
  // ---- fragment-major emit via LDS staging (per-wave, no cross-wave sharing) ----
  __shared__ short stage[4][8][520];         // 4 waves x 8 units x (512 + 8 pad) shorts = 33.3 KB
  short* BF0 = (short*)Zt;                   // path 0: seasonal
  const size_t PATH = (size_t)Bn * Cn * Ln;  // shorts per path
  int cq = (t & 15) >> 2;                    // unit n-part within wave
  int u = cq * 2 + (sub >> 1);               // unit index 0..7
  int hb = (sub & 1) * 2;                    // hi base {0, 2}
  // pass 1: seasonal
#pragma unroll
  for (int i = 0; i < 4; ++i) {
    int frv = (c4 & 15) + i;
    *reinterpret_cast<bf16x8*>(&stage[ty][u][(hb * 16 + frv) * 8]) = vs[i][0];
    *reinterpret_cast<bf16x8*>(&stage[ty][u][((hb + 1) * 16 + frv) * 8]) = vs[i][1];
  }
#pragma unroll
  for (int uu = 0; uu < 8; ++uu) {
    size_t nt = (size_t)b * 4 + (uu >> 1), ktg = (size_t)s * 2 + (uu & 1);
    *reinterpret_cast<bf16x8*>(BF0 + ((nt * 128 + ktg) << 9) + ((size_t)t << 3)) =
        *reinterpret_cast<const bf16x8*>(&stage[ty][uu][t * 8]);
  }
  // pass 2: trend (reuse buffer; wave-local ordering via lgkmcnt, no barrier needed)
#pragma unroll
  for (int i = 0; i < 4; ++i) {
    int frv = (c4 & 15) + i;
    *reinterpret_cast<bf16x8*>(&stage[ty][u][(hb * 16 + frv) * 8]) = vt[i][0];
    *reinterpret_cast<bf16x8*>(&stage[ty][u][((hb + 1) * 16 + frv) * 8]) = vt[i][1];
  }
#pragma unroll
  for (int uu = 0; uu < 8; ++uu) {
    size_t nt = (size_t)b * 4 + (uu >> 1), ktg = (size_t)s * 2 + (uu & 1);
    *reinterpret_cast<bf16x8*>(BF0 + PATH + ((nt * 128 + ktg) << 9) + ((size_t)t << 3)) =
        *reinterpret_cast<const bf16x8*>(&stage[ty][uu][t * 8]);
  }
}

// ---------------- kernel 5: bf16 MFMA GEMM — LDS-FREE, prefetch-1, lockstep barrier ----------------
// Reverted to the proven (256,3) config (r12: 39 µs, MfmaUtil 24%, 0 conflicts). fp16 Osr kept.
template <int KS>
__global__ void __launch_bounds__(256, 3) k_gemm(const bf16_t* __restrict__ Wt, const bf16_t* __restrict__ Zt,
                                                 __half* __restrict__ Osr) {
  // XCD-chunked bijective swizzle (gridDim.x % 8 == 0)
  int per = gridDim.x >> 3;
  int swz = (blockIdx.x & 7) * per + (blockIdx.x >> 3);
  int z = swz / 96, rem = swz % 96;                   // 96 = 16 x-blocks * 6 y-blocks
  int by = rem >> 4, bx = rem & 15;
  int p = z / KS, kq = z % KS;
  const short* AF = (const short*)Wt + (size_t)p * HPn * Ln;
  const short* BF = (const short*)Zt + (size_t)p * (Bn * Cn) * Ln;
  int h0 = by * 128, n0 = bx * 128;
  int kbase = kq * (Ln / KS);
  const int NT = (Ln / KS) / 32;                      // K-steps of 32 (even)
  int tid = threadIdx.x, wid = tid >> 6, lane = tid & 63;
  int wr = wid >> 1, wc = wid & 1;
  int fr = lane & 15, hi = lane >> 4;
  const short* ab = AF + ((((size_t)(h0 >> 4) + wr * 4) * 128 + (kbase >> 5)) << 9) + ((size_t)lane << 3);
  const short* bb = BF + ((((size_t)(n0 >> 4) + wc * 4) * 128 + (kbase >> 5)) << 9) + ((size_t)lane << 3);

  f32x4 acc[4][4];
#pragma unroll
  for (int i = 0; i < 4; ++i)
#pragma unroll
    for (int j = 0; j < 4; ++j) acc[i][j] = (f32x4){0.f, 0.f, 0.f, 0.f};

  auto LOAD = [&](bf16x8 (&a)[4], bf16x8 (&b)[4], int kt) {
#pragma unroll
    for (int i = 0; i < 4; ++i)
      a[i] = *reinterpret_cast<const bf16x8*>(ab + (((size_t)i * 128 + kt) << 9));
#pragma unroll
    for (int j = 0; j < 4; ++j)
      b[j] = *reinterpret_cast<const bf16x8*>(bb + (((size_t)j * 128 + kt) << 9));
  };
  auto COMPUTE = [&](const bf16x8 (&a)[4], const bf16x8 (&b)[4]) {
    __builtin_amdgcn_s_setprio(1);
#pragma unroll
    for (int i = 0; i < 4; ++i)
#pragma unroll
      for (int j = 0; j < 4; ++j)
        acc[i][j] = __builtin_amdgcn_mfma_f32_16x16x32_bf16(a[i], b[j], acc[i][j], 0, 0, 0);
    __builtin_amdgcn_s_setprio(0);
  };

  bf16x8 aA[4], bA[4], aB[4], bB[4];                  // named double buffers (rule #20)
  LOAD(aA, bA, 0);
  for (int t = 0; t < NT; t += 2) {
    if (t + 1 < NT) LOAD(aB, bB, t + 1);
    __builtin_amdgcn_s_barrier();                     // lockstep: align waves' load windows
    COMPUTE(aA, bA);
    if (t + 2 < NT) LOAD(aA, bA, t + 2);
    __builtin_amdgcn_s_barrier();
    if (t + 1 < NT) COMPUTE(aB, bB);
  }

#pragma unroll
  for (int i = 0; i < 4; ++i) {
#pragma unroll
    for (int j = 0; j < 4; ++j) {
#pragma unroll
      for (int r = 0; r < 4; ++r) {
        int m = wr * 64 + i * 16 + hi * 4 + r;
        int h = h0 + m;
        if (h < Hn) {
          int n = n0 + wc * 64 + j * 16 + fr;
          int bidx = n >> 6, c = n & 63;
          Osr[(((size_t)z * Bn + bidx) * Hn + h) * Cn + c] = __float2half(acc[i][j][r]);
        }
      }
    }
  }
}

// ---------------- kernel 6: epilogue — 32 rows/block, fp16 Osr reads ----------
template <int KS>
__global__ void __launch_bounds__(256) k_epi(const __half* __restrict__ Osr, const float* __restrict__ M,
                                             const float* __restrict__ cvec, const float* __restrict__ S,
                                             const float* __restrict__ st_b, const float* __restrict__ tt_b,
                                             const float* __restrict__ rev_w, const float* __restrict__ rev_b,
                                             const float* __restrict__ mean, const float* __restrict__ stdv,
                                             float* __restrict__ out) {
  __shared__ float Msh[2][64][64];    // 32 KB
  __shared__ float rowS[32][64];      // 8 KB
  __shared__ float rowT[32][64];      // 8 KB
  int t = threadIdx.x;
  for (int i = t; i < 2048; i += 256)   // vectorized Msh stage (8 x b128 per thread)
    reinterpret_cast<f32x4*>(Msh)[i] = reinterpret_cast<const f32x4*>(M)[i];
  int c = t & 63, grp = t >> 6;       // grp 0..3, 8 rows each
  float w = rev_w[c], rb = rev_b[c];
  float cs = cvec[c], ct = cvec[64 + c];
  int base = blockIdx.x * 32;
#pragma unroll
  for (int k = 0; k < 8; ++k) {
    int rl = grp * 8 + k;
    int r = base + rl;
    int b = r / 720, h = r % 720;
    float vs = 0.f, vt = 0.f;
#pragma unroll
    for (int kq = 0; kq < KS; ++kq) {
      vs += __half2float(Osr[(((size_t)kq * Bn + b) * Hn + h) * Cn + c]);
      vt += __half2float(Osr[(((size_t)(KS + kq) * Bn + b) * Hn + h) * Cn + c]);
    }
    rowS[rl][c] = vs;
    rowT[rl][c] = vt;
  }
  __syncthreads();
  float acc[8];
  int hh[8], bb[8];
#pragma unroll
  for (int k = 0; k < 8; ++k) {
    int r = base + grp * 8 + k;
    bb[k] = r / 720; hh[k] = r % 720;
    acc[k] = cs * S[hh[k]] + ct * S[768 + hh[k]] + st_b[hh[k]] + tt_b[hh[k]];
  }
  int r0 = grp * 8;
  for (int cq = 0; cq < 16; ++cq) {
    f32x4 rs[8], rt[8];
#pragma unroll
    for (int k = 0; k < 8; ++k) rs[k] = *reinterpret_cast<const f32x4*>(&rowS[r0 + k][cq * 4]);
#pragma unroll
    for (int k = 0; k < 8; ++k) rt[k] = *reinterpret_cast<const f32x4*>(&rowT[r0 + k][cq * 4]);
#pragma unroll
    for (int i = 0; i < 4; ++i) {
      float m0 = Msh[0][cq * 4 + i][c], m1 = Msh[1][cq * 4 + i][c];
#pragma unroll
      for (int k = 0; k < 8; ++k)
        acc[k] = fmaf(rs[k][i], m0, fmaf(rt[k][i], m1, acc[k]));
    }
  }
  float winv = 1.f / (w + EPSf);
#pragma unroll
  for (int k = 0; k < 8; ++k) {
    float o = (acc[k] - rb) * winv * stdv[bb[k] * Cn + c] + mean[bb[k] * Cn + c];
    out[(size_t)(base + r0 + k) * 64 + c] = o;
  }
}

// ---------------- launch ----------------
extern "C" void kernel_launch(void* const* d_in, const int* in_sizes, int n_in,
                              void* d_out, int out_size, void* d_ws, size_t ws_size,
                              hipStream_t stream) {
  const float* x     = (const float*)d_in[0];
  const float* alpha = (const float*)d_in[1];
  const float* rev_w = (const float*)d_in[2];
  const float* rev_b = (const float*)d_in[3];
  const float* se_w  = (const float*)d_in[4];
  const float* se_b  = (const float*)d_in[5];
  const float* sp_w  = (const float*)d_in[6];
  const float* sp_b  = (const float*)d_in[7];
  const float* st_w  = (const float*)d_in[8];
  const float* st_b  = (const float*)d_in[9];
  const float* te_w  = (const float*)d_in[10];
  const float* te_b  = (const float*)d_in[11];
  const float* tp_w  = (const float*)d_in[12];
  const float* tp_b  = (const float*)d_in[13];
  const float* tt_w  = (const float*)d_in[14];
  const float* tt_b  = (const float*)d_in[15];
  float* out = (float*)d_out;

  const size_t SZ_WT  = (size_t)2 * HPn * Ln * 2;          // 12.58 MB (fragment-major AF)
  const size_t SZ_ZT  = (size_t)2 * Bn * Cn * Ln * 2;      // 33.55 MB (fragment-major BF)
  const size_t SZ_SEG = (size_t)Bn * 64 * 64 * 4;          // 0.5 MB seg-level scratch
  const size_t SZ_M   = 2 * 64 * 64 * 4;                   // 32 KB
  const size_t SZ_CV  = 2 * 64 * 4;
  const size_t SZ_S   = 2 * 768 * 4;
  const size_t SZ_SP  = (size_t)2 * 64 * 768 * 4;          // Spart 393 KB
  const size_t TAIL   = SZ_M + SZ_CV + SZ_S + SZ_SP + 3 * (size_t)Bn * Cn * 4;

  // fp16 Osr: KS=4 needs 8 slices x 2B; scan scratch (6 MB) still fits in the Osr region.
  const size_t NEED4 = SZ_WT + SZ_ZT + 8 * OSR_SLICE * 2 + TAIL;
  const int KS = (ws_size >= NEED4) ? 4 : 1;
  size_t SZ_OSR = (size_t)(2 * KS) * OSR_SLICE * 2;
  const size_t SZ_SCRATCH = 4 * SZ_SEG + 4 * SZ_SEG;       // Psub(4) + Pseg/Ssum/Ssq/Carry(4)
  if (SZ_OSR < SZ_SCRATCH) SZ_OSR = SZ_SCRATCH;            // region shared with scan scratch

  char* ws = (char*)d_ws;
  bf16_t* Wt   = (bf16_t*)(ws);
  bf16_t* Zt   = (bf16_t*)(ws + SZ_WT);
  __half* Osr  = (__half*)(ws + SZ_WT + SZ_ZT);
  // scan scratch aliases Osr (dead before k_gemm writes Osr)
  float*  Psub  = (float*)Osr;                             // 2 MB
  float*  Pseg  = (float*)((char*)Psub + 4 * SZ_SEG);
  float*  Ssum  = (float*)((char*)Pseg + SZ_SEG);
  float*  Ssq   = (float*)((char*)Ssum + SZ_SEG);
  float*  Carry = (float*)((char*)Ssq + SZ_SEG);
  char* tail = ws + SZ_WT + SZ_ZT + SZ_OSR;
  float* Mbuf = (float*)tail;                 tail += SZ_M;
  float* cvec = (float*)tail;                 tail += SZ_CV;
  float* S    = (float*)tail;                 tail += SZ_S;
  float* Spart = (float*)tail;                tail += SZ_SP;
  float* mean = (float*)tail;                 tail += (size_t)Bn * Cn * 4;
  float* rstd = (float*)tail;                 tail += (size_t)Bn * Cn * 4;
  float* stdv = (float*)tail;

  k_preA<<<2048, 256, 0, stream>>>(st_w, tt_w, x, alpha, Wt, Spart, Psub, Pseg, Ssum, Ssq);
  k_mid<<<16, 256, 0, stream>>>(x, alpha, rev_w, rev_b, Pseg, Ssum, Ssq,
                                se_w, sp_w, se_b, sp_b, te_w, tp_w, te_b, tp_b, Spart,
                                mean, rstd, stdv, Carry, Mbuf, cvec, S);
  k_scanC<<<dim3(32, 16), dim3(64, 4), 0, stream>>>(x, alpha, rev_w, rev_b, mean, rstd, Carry, Psub, Zt);
  if (KS == 4) {
    k_gemm<4><<<768, 256, 0, stream>>>(Wt, Zt, Osr);
    k_epi<4><<<720, 256, 0, stream>>>(Osr, Mbuf, cvec, S, st_b, tt_b, rev_w, rev_b, mean, stdv, out);
  } else {
    k_gemm<1><<<192, 256, 0, stream>>>(Wt, Zt, Osr);
    k_epi<1><<<720, 256, 0, stream>>>(Osr, Mbuf, cvec, S, st_b, tt_b, rev_w, rev_b, mean, stdv, out);
  }
}